// Round 4
// baseline (594.796 us; speedup 1.0000x reference)
//
#include <hip/hip_runtime.h>
#include <math.h>

// Problem shape (fixed by setup_inputs): logits [8,12,256,256] fp32, targets [8,256,256] i32.
constexpr int B_  = 8;
constexpr int C_  = 12;
constexpr int H_  = 256;
constexpr int W_  = 256;
constexpr int HW_ = H_ * W_;
constexpr int NBC_ = B_ * C_;           // 96
constexpr int PAD_ = 256;               // LDS row padding (covers max radius 255)
constexpr int VB_  = NBC_ * 4;          // vert tiles (384): 64 columns per tile
constexpr int SMB_ = B_ * (HW_ / 1024); // softmax-stats blocks (512, 4 px/thread)
constexpr int EDTB_ = NBC_ * H_ / 4;    // k_edt blocks (6144)

// Packed vertical-EDT value: bit15 = is_fg (t==c); bits[14:0] = vertical
// distance d to nearest zero of the pixel's own nonzero transform
// (0x7FFF = no zero in column -> reference g = 1e6 - h). The OTHER
// transform's g is always 0 at this pixel, so one u16 encodes both.

// ---------------------------------------------------------------------------
// K1 (merged): blocks [0,384) = vertical EDT (64 cols x 8 segments, 2 adjacent
// columns/thread -> int2 loads, packed u32 stores); blocks [384,384+512) =
// per-pixel softmax stats den = {max, 1/sum}, float4 (4 px/thread).
// Block 0 zeroes the done-counter consumed by k_edt's last-block reduction.
// ---------------------------------------------------------------------------
__global__ void __launch_bounds__(256) k_vp(
                     const int* __restrict__ t,
                     const float* __restrict__ logits,
                     unsigned short* __restrict__ gpk,
                     int* __restrict__ hasfg_p,
                     float2* __restrict__ den,
                     int* __restrict__ cnt) {
    int tid = threadIdx.x;
    if (blockIdx.x >= VB_) {
        // ---- softmax-stats branch (float4: 4 pixels per thread) ----
        int pb = blockIdx.x - VB_;             // [0, 512)
        int b = pb >> 6;
        int p = ((pb & 63) << 10) + tid * 4;
        const float* lb = logits + (size_t)b * C_ * HW_ + p;
        float4 l[C_];
        float4 mx = make_float4(-3.4e38f, -3.4e38f, -3.4e38f, -3.4e38f);
        #pragma unroll
        for (int c = 0; c < C_; ++c) {
            l[c] = *(const float4*)(lb + (size_t)c * HW_);
            mx.x = fmaxf(mx.x, l[c].x);
            mx.y = fmaxf(mx.y, l[c].y);
            mx.z = fmaxf(mx.z, l[c].z);
            mx.w = fmaxf(mx.w, l[c].w);
        }
        float4 s = make_float4(0.f, 0.f, 0.f, 0.f);
        #pragma unroll
        for (int c = 0; c < C_; ++c) {
            s.x += __expf(l[c].x - mx.x);
            s.y += __expf(l[c].y - mx.y);
            s.z += __expf(l[c].z - mx.z);
            s.w += __expf(l[c].w - mx.w);
        }
        float2* dp = den + (size_t)b * HW_ + p;
        ((float4*)dp)[0] = make_float4(mx.x, 1.0f / s.x, mx.y, 1.0f / s.y);
        ((float4*)dp)[1] = make_float4(mx.z, 1.0f / s.z, mx.w, 1.0f / s.w);
        return;
    }

    // ---- vertical EDT branch: 2 adjacent columns per thread ----
    if (blockIdx.x == 0 && tid == 0) *cnt = 0;        // reset done-counter
    constexpr int SEG = 8, SH = 32;
    int s  = tid >> 5;          // segment
    int wl = tid & 31;          // column-pair within tile
    int blk = blockIdx.x;       // 96*4
    int bc = blk >> 2;
    int w0 = (blk & 3) * 64;
    int b = bc / C_, c = bc - b * C_;
    int w = w0 + 2 * wl;        // even
    const int* base = t + b * HW_ + w;
    int h0 = s * SH;

    unsigned tp0[SH / 4], tp1[SH / 4];
    int le0 = -1, ln0 = -1, fe0 = 256, fn0 = 256;
    int le1 = -1, ln1 = -1, fe1 = 256, fn1 = 256;
    #pragma unroll
    for (int i = 0; i < SH; ++i) {
        int2 tv = *(const int2*)(base + (h0 + i) * W_);
        if ((i & 3) == 0) { tp0[i >> 2] = 0; tp1[i >> 2] = 0; }
        tp0[i >> 2] |= (unsigned)tv.x << ((i & 3) * 8);
        tp1[i >> 2] |= (unsigned)tv.y << ((i & 3) * 8);
        int h = h0 + i;
        if (tv.x == c) { le0 = h; if (fe0 == 256) fe0 = h; }
        else           { ln0 = h; if (fn0 == 256) fn0 = h; }
        if (tv.y == c) { le1 = h; if (fe1 == 256) fe1 = h; }
        else           { ln1 = h; if (fn1 == 256) fn1 = h; }
    }
    __shared__ int sLE[SEG][64], sLN[SEG][64], sFE[SEG][64], sFN[SEG][64];
    sLE[s][2 * wl] = le0; sLE[s][2 * wl + 1] = le1;
    sLN[s][2 * wl] = ln0; sLN[s][2 * wl + 1] = ln1;
    sFE[s][2 * wl] = fe0; sFE[s][2 * wl + 1] = fe1;
    sFN[s][2 * wl] = fn0; sFN[s][2 * wl + 1] = fn1;
    __syncthreads();

    int carLE0 = -1, carLN0 = -1, carLE1 = -1, carLN1 = -1;
    for (int q = 0; q < s; ++q) {
        carLE0 = max(carLE0, sLE[q][2 * wl]);
        carLN0 = max(carLN0, sLN[q][2 * wl]);
        carLE1 = max(carLE1, sLE[q][2 * wl + 1]);
        carLN1 = max(carLN1, sLN[q][2 * wl + 1]);
    }
    int carFE0 = 256, carFN0 = 256, carFE1 = 256, carFN1 = 256;
    for (int q = s + 1; q < SEG; ++q) {
        carFE0 = min(carFE0, sFE[q][2 * wl]);
        carFN0 = min(carFN0, sFN[q][2 * wl]);
        carFE1 = min(carFE1, sFE[q][2 * wl + 1]);
        carFN1 = min(carFN1, sFN[q][2 * wl + 1]);
    }

    // tile has-fg: wave 0, column = tid (64 columns)
    bool pred = false;
    if (tid < 64) {
        int m = -1;
        #pragma unroll
        for (int q = 0; q < SEG; ++q) m = max(m, sLE[q][tid]);
        pred = (m >= 0);
    }
    bool anyfg = __any(pred);
    if (tid == 0) hasfg_p[blk] = anyfg ? 1 : 0;

    // forward pass: u8-encode dl-1 (255 = no zero at-or-above)
    unsigned ap0[SH / 4], ap1[SH / 4];
    {
        int l0 = carLE0, n0 = carLN0, l1 = carLE1, n1 = carLN1;
        #pragma unroll
        for (int i = 0; i < SH; ++i) {
            int h = h0 + i;
            int tv0 = (tp0[i >> 2] >> ((i & 3) * 8)) & 0xFF;
            int tv1 = (tp1[i >> 2] >> ((i & 3) * 8)) & 0xFF;
            int lz0, lz1;
            if (tv0 == c) { l0 = h; lz0 = n0; } else { n0 = h; lz0 = l0; }
            if (tv1 == c) { l1 = h; lz1 = n1; } else { n1 = h; lz1 = l1; }
            unsigned a0 = (lz0 < 0) ? 255u : (unsigned)(h - lz0 - 1);
            unsigned a1 = (lz1 < 0) ? 255u : (unsigned)(h - lz1 - 1);
            if ((i & 3) == 0) { ap0[i >> 2] = 0; ap1[i >> 2] = 0; }
            ap0[i >> 2] |= a0 << ((i & 3) * 8);
            ap1[i >> 2] |= a1 << ((i & 3) * 8);
        }
    }
    // backward pass: d = min(dl, dn), packed u32 store (2 cols)
    {
        int fe0_ = carFE0, fn0_ = carFN0, fe1_ = carFE1, fn1_ = carFN1;
        unsigned* gk32 = (unsigned*)(gpk + (size_t)bc * HW_ + w);
        #pragma unroll
        for (int i = SH - 1; i >= 0; --i) {
            int h = h0 + i;
            int tv0 = (tp0[i >> 2] >> ((i & 3) * 8)) & 0xFF;
            int tv1 = (tp1[i >> 2] >> ((i & 3) * 8)) & 0xFF;
            int nz0, nz1; bool fg0, fg1;
            if (tv0 == c) { fe0_ = h; fg0 = true;  nz0 = fn0_; }
            else          { fn0_ = h; fg0 = false; nz0 = fe0_; }
            if (tv1 == c) { fe1_ = h; fg1 = true;  nz1 = fn1_; }
            else          { fn1_ = h; fg1 = false; nz1 = fe1_; }
            unsigned au0 = (ap0[i >> 2] >> ((i & 3) * 8)) & 0xFF;
            unsigned au1 = (ap1[i >> 2] >> ((i & 3) * 8)) & 0xFF;
            int dl0 = (au0 == 255u) ? 0x7FFF : (int)au0 + 1;
            int dl1 = (au1 == 255u) ? 0x7FFF : (int)au1 + 1;
            int dn0 = (nz0 > 255) ? 0x7FFF : (nz0 - h);
            int dn1 = (nz1 > 255) ? 0x7FFF : (nz1 - h);
            unsigned d0 = (unsigned)min(dl0, dn0) | (fg0 ? 0x8000u : 0u);
            unsigned d1 = (unsigned)min(dl1, dn1) | (fg1 ? 0x8000u : 0u);
            gk32[(h * W_) >> 1] = d0 | (d1 << 16);
        }
    }
}

// ---------------------------------------------------------------------------
// K2 (fused): per-row horizontal EDT + own-class prob + raw dice sums, then
// last-block-done final reduction (replaces the k_bcred dispatch).
// - neg/pos parabola scans merged into ONE loop with independent active
//   flags: per-transform update sequences unchanged (bit-identical), but
//   the two latency-bound LDS-read chains interleave -> 2x ILP.
// - Last block (device-scope counter) re-reads all partials and computes
//   the 96 dice terms exactly as k_bcred did, writing out[0] directly.
//   Deadlock-free: no block ever waits on an unscheduled block.
// ---------------------------------------------------------------------------
__global__ void __launch_bounds__(256) k_edt(
                      const unsigned short* __restrict__ gpk,
                      const float* __restrict__ logits,
                      const float2* __restrict__ den,
                      const int* __restrict__ hasfg_p,
                      float* __restrict__ part,
                      int* __restrict__ cnt,
                      float* __restrict__ out) {
    __shared__ float sp[4][W_ + 2 * PAD_];
    __shared__ float sn[4][W_ + 2 * PAD_];
    __shared__ float red[4][7];
    __shared__ int sLast;
    int wave = threadIdx.x >> 6;
    int lane = threadIdx.x & 63;
    int tid  = threadIdx.x;
    int row = blockIdx.x * 4 + wave;       // bc*256 + h; all 4 rows same bc
    int bc = row >> 8;
    int b = bc / C_, c = bc - b * C_;
    int h = row & (H_ - 1);

    int hfl = 0;
    if (lane < 4) hfl = hasfg_p[bc * 4 + lane];
    bool hf = __any(hfl != 0);             // uniform across block (same bc)

    // hoist independent prob-path loads: latency hides under the EDT scans
    const float*  lrow = logits + ((size_t)b * C_ + c) * HW_ + h * W_;
    const float2* drow = den + (size_t)b * HW_ + h * W_;
    float lv[4]; float2 mv[4];
    #pragma unroll
    for (int i = 0; i < 4; ++i) {
        int j = lane + 64 * i;
        lv[i] = lrow[j];
        mv[i] = drow[j];
    }

    float dv[4];
    if (hf) {
        const ushort4 v4 = ((const ushort4*)(gpk + (size_t)row * W_))[lane];

        float4 inf4 = make_float4(3.0e38f, 3.0e38f, 3.0e38f, 3.0e38f);
        ((float4*)&sp[wave][0])[lane]          = inf4;
        ((float4*)&sp[wave][PAD_ + W_])[lane]  = inf4;
        ((float4*)&sn[wave][0])[lane]          = inf4;
        ((float4*)&sn[wave][PAD_ + W_])[lane]  = inf4;

        float s1 = (float)(1000000 - h);
        float sent2 = s1 * s1;             // == fl((1e6 - h)^2), reference-exact
        float4 fpv, fnv;
        {
            const unsigned short* vs = (const unsigned short*)&v4;
            float* fp = (float*)&fpv;
            float* fn = (float*)&fnv;
            #pragma unroll
            for (int q = 0; q < 4; ++q) {
                unsigned v = vs[q];
                unsigned d = v & 0x7FFFu;
                float g2 = (d == 0x7FFFu) ? sent2 : (float)(d * d);
                bool fg = (v & 0x8000u) != 0;
                fp[q] = fg ? g2 : 0.0f;
                fn[q] = fg ? 0.0f : g2;
            }
        }
        ((float4*)&sp[wave][PAD_])[lane] = fpv;
        ((float4*)&sn[wave][PAD_])[lane] = fnv;
        // wave-private LDS rows: wave-local wait suffices (no barrier)
        asm volatile("s_waitcnt lgkmcnt(0)" ::: "memory");

        float bp[4], bn[4];
        #pragma unroll
        for (int i = 0; i < 4; ++i) {
            int j = PAD_ + lane + 64 * i;
            bp[i] = sp[wave][j];
            bn[i] = sn[wave][j];
        }
        // merged dual-transform scan: flags monotone, update order per
        // transform identical to two separate loops -> bit-identical result
        bool actN = true, actP = true;
        for (int r = 1; r < W_; ++r) {
            float fr = (float)r;
            float r2 = fr * fr;
            if (actN) {
                float m = fmaxf(fmaxf(bn[0], bn[1]), fmaxf(bn[2], bn[3]));
                if (!__any(r2 < m)) actN = false;
                else {
                    #pragma unroll
                    for (int i = 0; i < 4; ++i) {
                        int j = PAD_ + lane + 64 * i;
                        float v = fminf(sn[wave][j - r], sn[wave][j + r]);
                        bn[i] = fminf(bn[i], fmaf(fr, fr, v));
                    }
                }
            }
            if (actP) {
                float m = fmaxf(fmaxf(bp[0], bp[1]), fmaxf(bp[2], bp[3]));
                if (!__any(r2 < m)) actP = false;
                else {
                    #pragma unroll
                    for (int i = 0; i < 4; ++i) {
                        int j = PAD_ + lane + 64 * i;
                        float v = fminf(sp[wave][j - r], sp[wave][j + r]);
                        bp[i] = fminf(bp[i], fmaf(fr, fr, v));
                    }
                }
            }
            if (!actN && !actP) break;
        }
        #pragma unroll
        for (int i = 0; i < 4; ++i) dv[i] = sqrtf(bn[i]) - sqrtf(bp[i]);
    } else {
        #pragma unroll
        for (int i = 0; i < 4; ++i) dv[i] = 0.0f;
    }

    // own-class prob from precomputed stats + raw sums over 256 pixels
    float s_pd = 0.f, s_p = 0.f, s_pp = 0.f, s_d = 0.f, s_dd = 0.f;
    float mn = 3.4e38f, mx = -3.4e38f;
    #pragma unroll
    for (int i = 0; i < 4; ++i) {
        float2 mi = mv[i];
        float pr = __expf(lv[i] - mi.x) * mi.y;
        float d = dv[i];
        s_pd = fmaf(pr, d, s_pd);
        s_p += pr;
        s_pp = fmaf(pr, pr, s_pp);
        s_d += d;
        s_dd = fmaf(d, d, s_dd);
        mn = fminf(mn, d);
        mx = fmaxf(mx, d);
    }
    #pragma unroll
    for (int off = 32; off; off >>= 1) {
        s_pd += __shfl_down(s_pd, off);
        s_p  += __shfl_down(s_p, off);
        s_pp += __shfl_down(s_pp, off);
        s_d  += __shfl_down(s_d, off);
        s_dd += __shfl_down(s_dd, off);
        mn = fminf(mn, __shfl_down(mn, off));
        mx = fmaxf(mx, __shfl_down(mx, off));
    }
    if (lane == 0) {
        float* p8 = part + (size_t)row * 8;
        p8[0] = s_pd; p8[1] = s_p; p8[2] = s_pp;
        p8[3] = s_d;  p8[4] = s_dd; p8[5] = mn; p8[6] = mx;
    }

    // ---- last-block-done final reduction (replaces k_bcred dispatch) ----
    __threadfence();                        // release this block's partials
    __syncthreads();
    if (tid == 0) {
        int old = atomicAdd(cnt, 1);        // device-scope by default
        sLast = (old == (int)gridDim.x - 1) ? 1 : 0;
    }
    __syncthreads();
    if (sLast) {
        __threadfence();                    // acquire all blocks' partials
        float loss = 0.0f;                  // meaningful in thread 0 only
        for (int rbc = 0; rbc < NBC_; ++rbc) {
            const float* p8 = part + ((size_t)rbc * 256 + tid) * 8;
            float r_pd = p8[0], r_p = p8[1], r_pp = p8[2];
            float r_d = p8[3], r_dd = p8[4], rmn = p8[5], rmx = p8[6];
            #pragma unroll
            for (int off = 32; off; off >>= 1) {
                r_pd += __shfl_down(r_pd, off);
                r_p  += __shfl_down(r_p, off);
                r_pp += __shfl_down(r_pp, off);
                r_d  += __shfl_down(r_d, off);
                r_dd += __shfl_down(r_dd, off);
                rmn = fminf(rmn, __shfl_down(rmn, off));
                rmx = fmaxf(rmx, __shfl_down(rmx, off));
            }
            if (lane == 0) {
                red[wave][0] = r_pd; red[wave][1] = r_p; red[wave][2] = r_pp;
                red[wave][3] = r_d;  red[wave][4] = r_dd;
                red[wave][5] = rmn;  red[wave][6] = rmx;
            }
            __syncthreads();
            if (tid == 0) {
                r_pd = red[0][0]; r_p = red[0][1]; r_pp = red[0][2];
                r_d = red[0][3]; r_dd = red[0][4]; rmn = red[0][5]; rmx = red[0][6];
                for (int w2 = 1; w2 < 4; ++w2) {
                    r_pd += red[w2][0]; r_p += red[w2][1]; r_pp += red[w2][2];
                    r_d += red[w2][3]; r_dd += red[w2][4];
                    rmn = fminf(rmn, red[w2][5]); rmx = fmaxf(rmx, red[w2][6]);
                }
                float sc = 1.0f / (rmx - rmn + 1e-8f);
                float inter = sc * (r_pd - rmn * r_p);
                float d2 = sc * sc * (r_dd - 2.0f * rmn * r_d + rmn * rmn * (float)HW_);
                float dice = 2.0f * inter / (r_pp + d2 + 1e-6f);
                loss += (1.0f - dice) * (1.0f / (float)NBC_);
            }
            __syncthreads();                // red[] reused next iteration
        }
        if (tid == 0) out[0] = loss;
    }
}

// ---------------------------------------------------------------------------
extern "C" void kernel_launch(void* const* d_in, const int* in_sizes, int n_in,
                              void* d_out, int out_size, void* d_ws, size_t ws_size,
                              hipStream_t stream) {
    const float* logits  = (const float*)d_in[0];
    const int*   targets = (const int*)d_in[1];
    float* out = (float*)d_out;

    // ws layout: gpk u16[96*65536] | hasfg_p i32[768] | part f32[24576*8] |
    //            den float2[8*65536] | cnt i32
    unsigned short* gpk = (unsigned short*)d_ws;
    int* hasfg_p = (int*)(gpk + (size_t)NBC_ * HW_);
    float* part = (float*)(hasfg_p + NBC_ * 8);
    float2* den = (float2*)(part + (size_t)NBC_ * H_ * 8);
    int* cnt = (int*)(den + (size_t)B_ * HW_);

    k_vp<<<VB_ + SMB_, 256, 0, stream>>>(targets, logits, gpk,
                                         hasfg_p, den, cnt);
    k_edt<<<EDTB_, 256, 0, stream>>>(gpk, logits, den, hasfg_p, part, cnt, out);
}

// Round 5
// 115.863 us; speedup vs baseline: 5.1336x; 5.1336x over previous
//
#include <hip/hip_runtime.h>
#include <math.h>

// Problem shape (fixed by setup_inputs): logits [8,12,256,256] fp32, targets [8,256,256] i32.
constexpr int B_  = 8;
constexpr int C_  = 12;
constexpr int H_  = 256;
constexpr int W_  = 256;
constexpr int HW_ = H_ * W_;
constexpr int NBC_ = B_ * C_;           // 96
constexpr int PAD_ = 256;               // LDS row padding (covers max radius 255)
constexpr int VB_  = NBC_ * 4;          // vert tiles (384): 64 columns per tile
constexpr int E2B_ = B_ * H_;           // k_edt2 blocks (2048): one (b,h) row each

// Packed vertical-EDT value: bit15 = is_fg (t==c); bits[14:0] = vertical
// distance d to nearest zero of the pixel's own nonzero transform
// (0x7FFF = no zero in column -> reference g = 1e6 - h). The OTHER
// transform's g is always 0 at this pixel, so one u16 encodes both.

// ---------------------------------------------------------------------------
// K1: vertical EDT only (384 blocks; 64 cols x 8 segments, 2 adjacent
// columns/thread -> int2 loads, packed u32 stores). Softmax-stats branch is
// GONE: k_edt2 now computes softmax in-register from the 12 logit rows,
// eliminating the den buffer (4.2 MB write + ~50 MB 12x re-read).
// Block 0 zeroes out[0] (consumed by k_bcred two dispatches later).
// ---------------------------------------------------------------------------
__global__ void __launch_bounds__(256) k_vp(
                     const int* __restrict__ t,
                     unsigned short* __restrict__ gpk,
                     int* __restrict__ hasfg_p,
                     float* __restrict__ out) {
    int tid = threadIdx.x;
    if (blockIdx.x == 0 && tid == 0) out[0] = 0.0f;   // replaces memset dispatch
    constexpr int SEG = 8, SH = 32;
    int s  = tid >> 5;          // segment
    int wl = tid & 31;          // column-pair within tile
    int blk = blockIdx.x;       // 96*4
    int bc = blk >> 2;
    int w0 = (blk & 3) * 64;
    int b = bc / C_, c = bc - b * C_;
    int w = w0 + 2 * wl;        // even
    const int* base = t + b * HW_ + w;
    int h0 = s * SH;

    unsigned tp0[SH / 4], tp1[SH / 4];
    int le0 = -1, ln0 = -1, fe0 = 256, fn0 = 256;
    int le1 = -1, ln1 = -1, fe1 = 256, fn1 = 256;
    #pragma unroll
    for (int i = 0; i < SH; ++i) {
        int2 tv = *(const int2*)(base + (h0 + i) * W_);
        if ((i & 3) == 0) { tp0[i >> 2] = 0; tp1[i >> 2] = 0; }
        tp0[i >> 2] |= (unsigned)tv.x << ((i & 3) * 8);
        tp1[i >> 2] |= (unsigned)tv.y << ((i & 3) * 8);
        int h = h0 + i;
        if (tv.x == c) { le0 = h; if (fe0 == 256) fe0 = h; }
        else           { ln0 = h; if (fn0 == 256) fn0 = h; }
        if (tv.y == c) { le1 = h; if (fe1 == 256) fe1 = h; }
        else           { ln1 = h; if (fn1 == 256) fn1 = h; }
    }
    __shared__ int sLE[SEG][64], sLN[SEG][64], sFE[SEG][64], sFN[SEG][64];
    sLE[s][2 * wl] = le0; sLE[s][2 * wl + 1] = le1;
    sLN[s][2 * wl] = ln0; sLN[s][2 * wl + 1] = ln1;
    sFE[s][2 * wl] = fe0; sFE[s][2 * wl + 1] = fe1;
    sFN[s][2 * wl] = fn0; sFN[s][2 * wl + 1] = fn1;
    __syncthreads();

    int carLE0 = -1, carLN0 = -1, carLE1 = -1, carLN1 = -1;
    for (int q = 0; q < s; ++q) {
        carLE0 = max(carLE0, sLE[q][2 * wl]);
        carLN0 = max(carLN0, sLN[q][2 * wl]);
        carLE1 = max(carLE1, sLE[q][2 * wl + 1]);
        carLN1 = max(carLN1, sLN[q][2 * wl + 1]);
    }
    int carFE0 = 256, carFN0 = 256, carFE1 = 256, carFN1 = 256;
    for (int q = s + 1; q < SEG; ++q) {
        carFE0 = min(carFE0, sFE[q][2 * wl]);
        carFN0 = min(carFN0, sFN[q][2 * wl]);
        carFE1 = min(carFE1, sFE[q][2 * wl + 1]);
        carFN1 = min(carFN1, sFN[q][2 * wl + 1]);
    }

    // tile has-fg: wave 0, column = tid (64 columns)
    bool pred = false;
    if (tid < 64) {
        int m = -1;
        #pragma unroll
        for (int q = 0; q < SEG; ++q) m = max(m, sLE[q][tid]);
        pred = (m >= 0);
    }
    bool anyfg = __any(pred);
    if (tid == 0) hasfg_p[blk] = anyfg ? 1 : 0;

    // forward pass: u8-encode dl-1 (255 = no zero at-or-above)
    unsigned ap0[SH / 4], ap1[SH / 4];
    {
        int l0 = carLE0, n0 = carLN0, l1 = carLE1, n1 = carLN1;
        #pragma unroll
        for (int i = 0; i < SH; ++i) {
            int h = h0 + i;
            int tv0 = (tp0[i >> 2] >> ((i & 3) * 8)) & 0xFF;
            int tv1 = (tp1[i >> 2] >> ((i & 3) * 8)) & 0xFF;
            int lz0, lz1;
            if (tv0 == c) { l0 = h; lz0 = n0; } else { n0 = h; lz0 = l0; }
            if (tv1 == c) { l1 = h; lz1 = n1; } else { n1 = h; lz1 = l1; }
            unsigned a0 = (lz0 < 0) ? 255u : (unsigned)(h - lz0 - 1);
            unsigned a1 = (lz1 < 0) ? 255u : (unsigned)(h - lz1 - 1);
            if ((i & 3) == 0) { ap0[i >> 2] = 0; ap1[i >> 2] = 0; }
            ap0[i >> 2] |= a0 << ((i & 3) * 8);
            ap1[i >> 2] |= a1 << ((i & 3) * 8);
        }
    }
    // backward pass: d = min(dl, dn), packed u32 store (2 cols)
    {
        int fe0_ = carFE0, fn0_ = carFN0, fe1_ = carFE1, fn1_ = carFN1;
        unsigned* gk32 = (unsigned*)(gpk + (size_t)bc * HW_ + w);
        #pragma unroll
        for (int i = SH - 1; i >= 0; --i) {
            int h = h0 + i;
            int tv0 = (tp0[i >> 2] >> ((i & 3) * 8)) & 0xFF;
            int tv1 = (tp1[i >> 2] >> ((i & 3) * 8)) & 0xFF;
            int nz0, nz1; bool fg0, fg1;
            if (tv0 == c) { fe0_ = h; fg0 = true;  nz0 = fn0_; }
            else          { fn0_ = h; fg0 = false; nz0 = fe0_; }
            if (tv1 == c) { fe1_ = h; fg1 = true;  nz1 = fn1_; }
            else          { fn1_ = h; fg1 = false; nz1 = fe1_; }
            unsigned au0 = (ap0[i >> 2] >> ((i & 3) * 8)) & 0xFF;
            unsigned au1 = (ap1[i >> 2] >> ((i & 3) * 8)) & 0xFF;
            int dl0 = (au0 == 255u) ? 0x7FFF : (int)au0 + 1;
            int dl1 = (au1 == 255u) ? 0x7FFF : (int)au1 + 1;
            int dn0 = (nz0 > 255) ? 0x7FFF : (nz0 - h);
            int dn1 = (nz1 > 255) ? 0x7FFF : (nz1 - h);
            unsigned d0 = (unsigned)min(dl0, dn0) | (fg0 ? 0x8000u : 0u);
            unsigned d1 = (unsigned)min(dl1, dn1) | (fg1 ? 0x8000u : 0u);
            gk32[(h * W_) >> 1] = d0 | (d1 << 16);
        }
    }
}

// ---------------------------------------------------------------------------
// K2 (restructured): one block per (b,h) row; all 12 classes of that row.
// Softmax computed in-register (two passes over the 12 logit rows; pass 2
// reload is L1-hot). Each wave owns 3 classes (fully unrolled so the l3[]
// logit stash has static indices only — no scratch). Per class: horizontal
// EDT scan (R1's proven two-loop form) + pr sums -> part[row*8].
// Removes: den buffer (4.2 MB w + ~50 MB r), duplicate logits read (25 MB),
// and k_vp's 512-block softmax branch.
// ---------------------------------------------------------------------------
__global__ void __launch_bounds__(256) k_edt2(
                      const unsigned short* __restrict__ gpk,
                      const float* __restrict__ logits,
                      const int* __restrict__ hasfg_p,
                      float* __restrict__ part) {
    __shared__ float sp[4][W_ + 2 * PAD_];
    __shared__ float sn[4][W_ + 2 * PAD_];
    int tid  = threadIdx.x;
    int wave = tid >> 6;
    int lane = tid & 63;
    int blk = blockIdx.x;                  // [0, 2048)
    int b = blk >> 8;
    int h = blk & (H_ - 1);

    // pad init once per wave; pads are never overwritten by row data
    float4 inf4 = make_float4(3.0e38f, 3.0e38f, 3.0e38f, 3.0e38f);
    ((float4*)&sp[wave][0])[lane]          = inf4;
    ((float4*)&sp[wave][PAD_ + W_])[lane]  = inf4;
    ((float4*)&sn[wave][0])[lane]          = inf4;
    ((float4*)&sn[wave][PAD_ + W_])[lane]  = inf4;

    // ---- softmax stats in-register; pixels j = lane + 64*i (sum mapping) ----
    const float* lb = logits + (size_t)b * C_ * HW_ + h * W_;
    float mx4[4] = {-3.4e38f, -3.4e38f, -3.4e38f, -3.4e38f};
    #pragma unroll
    for (int c = 0; c < C_; ++c) {
        #pragma unroll
        for (int i = 0; i < 4; ++i)
            mx4[i] = fmaxf(mx4[i], lb[(size_t)c * HW_ + lane + 64 * i]);
    }
    float s4[4] = {0.f, 0.f, 0.f, 0.f};
    #pragma unroll
    for (int c = 0; c < C_; ++c) {
        #pragma unroll
        for (int i = 0; i < 4; ++i)
            s4[i] += __expf(lb[(size_t)c * HW_ + lane + 64 * i] - mx4[i]);
    }
    float inv4[4];
    #pragma unroll
    for (int i = 0; i < 4; ++i) inv4[i] = 1.0f / s4[i];

    // this wave's 3 classes: logit stash with static indices (L1-hot reload)
    int c0 = wave * 3;
    float l3[3][4];
    #pragma unroll
    for (int q = 0; q < 3; ++q)
        #pragma unroll
        for (int i = 0; i < 4; ++i)
            l3[q][i] = lb[(size_t)(c0 + q) * HW_ + lane + 64 * i];

    float s1 = (float)(1000000 - h);
    float sent2 = s1 * s1;                 // == fl((1e6 - h)^2), reference-exact

    #pragma unroll
    for (int q = 0; q < 3; ++q) {
        int c = c0 + q;
        int bc = b * C_ + c;
        int row = bc * H_ + h;

        int hfl = 0;
        if (lane < 4) hfl = hasfg_p[bc * 4 + lane];
        bool hf = __any(hfl != 0);         // uniform per wave

        float dv[4];
        if (hf) {
            const ushort4 v4 = ((const ushort4*)(gpk + (size_t)bc * HW_ + h * W_))[lane];
            float4 fpv, fnv;
            {
                const unsigned short* vs = (const unsigned short*)&v4;
                float* fp = (float*)&fpv;
                float* fn = (float*)&fnv;
                #pragma unroll
                for (int k2 = 0; k2 < 4; ++k2) {
                    unsigned v = vs[k2];
                    unsigned d = v & 0x7FFFu;
                    float g2 = (d == 0x7FFFu) ? sent2 : (float)(d * d);
                    bool fg = (v & 0x8000u) != 0;
                    fp[k2] = fg ? g2 : 0.0f;
                    fn[k2] = fg ? 0.0f : g2;
                }
            }
            ((float4*)&sp[wave][PAD_])[lane] = fpv;
            ((float4*)&sn[wave][PAD_])[lane] = fnv;
            // wave-private LDS rows: wave-local wait suffices (no barrier)
            asm volatile("s_waitcnt lgkmcnt(0)" ::: "memory");

            float bp[4], bn[4];
            #pragma unroll
            for (int i = 0; i < 4; ++i) {
                int j = PAD_ + lane + 64 * i;
                bp[i] = sp[wave][j];
                bn[i] = sn[wave][j];
            }
            for (int r = 1; r < W_; ++r) {
                float fr = (float)r;
                float r2 = fr * fr;
                float m = fmaxf(fmaxf(bn[0], bn[1]), fmaxf(bn[2], bn[3]));
                if (!__any(r2 < m)) break;
                #pragma unroll
                for (int i = 0; i < 4; ++i) {
                    int j = PAD_ + lane + 64 * i;
                    float v = fminf(sn[wave][j - r], sn[wave][j + r]);
                    bn[i] = fminf(bn[i], fmaf(fr, fr, v));
                }
            }
            for (int r = 1; r < W_; ++r) {
                float fr = (float)r;
                float r2 = fr * fr;
                float m = fmaxf(fmaxf(bp[0], bp[1]), fmaxf(bp[2], bp[3]));
                if (!__any(r2 < m)) break;
                #pragma unroll
                for (int i = 0; i < 4; ++i) {
                    int j = PAD_ + lane + 64 * i;
                    float v = fminf(sp[wave][j - r], sp[wave][j + r]);
                    bp[i] = fminf(bp[i], fmaf(fr, fr, v));
                }
            }
            #pragma unroll
            for (int i = 0; i < 4; ++i) dv[i] = sqrtf(bn[i]) - sqrtf(bp[i]);
        } else {
            #pragma unroll
            for (int i = 0; i < 4; ++i) dv[i] = 0.0f;
        }

        // own-class prob + raw sums over 256 pixels (order identical to R1)
        float s_pd = 0.f, s_p = 0.f, s_pp = 0.f, s_d = 0.f, s_dd = 0.f;
        float mn = 3.4e38f, mx = -3.4e38f;
        #pragma unroll
        for (int i = 0; i < 4; ++i) {
            float pr = __expf(l3[q][i] - mx4[i]) * inv4[i];
            float d = dv[i];
            s_pd = fmaf(pr, d, s_pd);
            s_p += pr;
            s_pp = fmaf(pr, pr, s_pp);
            s_d += d;
            s_dd = fmaf(d, d, s_dd);
            mn = fminf(mn, d);
            mx = fmaxf(mx, d);
        }
        #pragma unroll
        for (int off = 32; off; off >>= 1) {
            s_pd += __shfl_down(s_pd, off);
            s_p  += __shfl_down(s_p, off);
            s_pp += __shfl_down(s_pp, off);
            s_d  += __shfl_down(s_d, off);
            s_dd += __shfl_down(s_dd, off);
            mn = fminf(mn, __shfl_down(mn, off));
            mx = fmaxf(mx, __shfl_down(mx, off));
        }
        if (lane == 0) {
            float* p8 = part + (size_t)row * 8;
            p8[0] = s_pd; p8[1] = s_p; p8[2] = s_pp;
            p8[3] = s_d;  p8[4] = s_dd; p8[5] = mn; p8[6] = mx;
        }
    }
}

// ---------------------------------------------------------------------------
// K3: per-(b,c) reduce of 256 row partials -> dice -> atomicAdd loss term.
// out[0] zeroed by k_vp block 0. inter = sc*(S_pd - mn*S_p);
// d2 = sc^2*(S_dd - 2 mn S_d + mn^2 N). 96 atomics total.
// ---------------------------------------------------------------------------
__global__ void __launch_bounds__(256) k_bcred(
                       const float* __restrict__ part, float* __restrict__ out) {
    int bc = blockIdx.x;
    int tid = threadIdx.x;                 // 256
    const float* p8 = part + ((size_t)bc * 256 + tid) * 8;
    float s_pd = p8[0], s_p = p8[1], s_pp = p8[2];
    float s_d = p8[3], s_dd = p8[4], mn = p8[5], mx = p8[6];
    #pragma unroll
    for (int off = 32; off; off >>= 1) {
        s_pd += __shfl_down(s_pd, off);
        s_p  += __shfl_down(s_p, off);
        s_pp += __shfl_down(s_pp, off);
        s_d  += __shfl_down(s_d, off);
        s_dd += __shfl_down(s_dd, off);
        mn = fminf(mn, __shfl_down(mn, off));
        mx = fmaxf(mx, __shfl_down(mx, off));
    }
    __shared__ float red[4][7];
    int wave = tid >> 6, lane = tid & 63;
    if (lane == 0) {
        red[wave][0] = s_pd; red[wave][1] = s_p; red[wave][2] = s_pp;
        red[wave][3] = s_d;  red[wave][4] = s_dd; red[wave][5] = mn; red[wave][6] = mx;
    }
    __syncthreads();
    if (tid == 0) {
        s_pd = red[0][0]; s_p = red[0][1]; s_pp = red[0][2];
        s_d = red[0][3]; s_dd = red[0][4]; mn = red[0][5]; mx = red[0][6];
        for (int w = 1; w < 4; ++w) {
            s_pd += red[w][0]; s_p += red[w][1]; s_pp += red[w][2];
            s_d += red[w][3]; s_dd += red[w][4];
            mn = fminf(mn, red[w][5]); mx = fmaxf(mx, red[w][6]);
        }
        float sc = 1.0f / (mx - mn + 1e-8f);
        float inter = sc * (s_pd - mn * s_p);
        float d2 = sc * sc * (s_dd - 2.0f * mn * s_d + mn * mn * (float)HW_);
        float dice = 2.0f * inter / (s_pp + d2 + 1e-6f);
        atomicAdd(out, (1.0f - dice) * (1.0f / (float)NBC_));
    }
}

// ---------------------------------------------------------------------------
extern "C" void kernel_launch(void* const* d_in, const int* in_sizes, int n_in,
                              void* d_out, int out_size, void* d_ws, size_t ws_size,
                              hipStream_t stream) {
    const float* logits  = (const float*)d_in[0];
    const int*   targets = (const int*)d_in[1];
    float* out = (float*)d_out;

    // ws layout: gpk u16[96*65536] | hasfg_p i32[384] | part f32[24576*8]
    unsigned short* gpk = (unsigned short*)d_ws;
    int* hasfg_p = (int*)(gpk + (size_t)NBC_ * HW_);
    float* part = (float*)(hasfg_p + VB_);

    k_vp<<<VB_, 256, 0, stream>>>(targets, gpk, hasfg_p, out);
    k_edt2<<<E2B_, 256, 0, stream>>>(gpk, logits, hasfg_p, part);
    k_bcred<<<NBC_, 256, 0, stream>>>(part, out);
}

// Round 6
// 112.114 us; speedup vs baseline: 5.3053x; 1.0334x over previous
//
#include <hip/hip_runtime.h>
#include <math.h>

// Problem shape (fixed by setup_inputs): logits [8,12,256,256] fp32, targets [8,256,256] i32.
constexpr int B_  = 8;
constexpr int C_  = 12;
constexpr int H_  = 256;
constexpr int W_  = 256;
constexpr int HW_ = H_ * W_;
constexpr int NBC_ = B_ * C_;           // 96
constexpr int VB_  = NBC_ * 4;          // vert tiles (384): 64 columns per tile
constexpr int SMB_ = B_ * (HW_ / 1024); // softmax-stats blocks (512, 4 px/thread)
constexpr int LROW_ = 264;              // LDS row stride: data 0..255, inf @256,257

// Packed vertical-EDT value: bit15 = is_fg (t==c); bits[14:0] = vertical
// distance d to nearest zero of the pixel's own nonzero transform
// (0x7FFF = no zero in column -> reference g = 1e6 - h). The OTHER
// transform's g is always 0 at this pixel, so one u16 encodes both.

// ---------------------------------------------------------------------------
// K1 (merged): blocks [0,384) = vertical EDT scans (64 cols x 8 segments,
// 2 adjacent columns per thread -> int2 loads, packed u32 stores);
// blocks [384, 384+512) = per-pixel softmax stats den = {max, 1/sum},
// float4 (4 px/thread). Block 0 zeroes out[0] (consumed by k_bcred).
// ---------------------------------------------------------------------------
__global__ void __launch_bounds__(256) k_vp(
                     const int* __restrict__ t,
                     const float* __restrict__ logits,
                     unsigned short* __restrict__ gpk,
                     int* __restrict__ hasfg_p,
                     float2* __restrict__ den,
                     float* __restrict__ out) {
    int tid = threadIdx.x;
    if (blockIdx.x >= VB_) {
        // ---- softmax-stats branch (float4: 4 pixels per thread) ----
        int pb = blockIdx.x - VB_;             // [0, 512)
        int b = pb >> 6;
        int p = ((pb & 63) << 10) + tid * 4;
        const float* lb = logits + (size_t)b * C_ * HW_ + p;
        float4 l[C_];
        float4 mx = make_float4(-3.4e38f, -3.4e38f, -3.4e38f, -3.4e38f);
        #pragma unroll
        for (int c = 0; c < C_; ++c) {
            l[c] = *(const float4*)(lb + (size_t)c * HW_);
            mx.x = fmaxf(mx.x, l[c].x);
            mx.y = fmaxf(mx.y, l[c].y);
            mx.z = fmaxf(mx.z, l[c].z);
            mx.w = fmaxf(mx.w, l[c].w);
        }
        float4 s = make_float4(0.f, 0.f, 0.f, 0.f);
        #pragma unroll
        for (int c = 0; c < C_; ++c) {
            s.x += __expf(l[c].x - mx.x);
            s.y += __expf(l[c].y - mx.y);
            s.z += __expf(l[c].z - mx.z);
            s.w += __expf(l[c].w - mx.w);
        }
        float2* dp = den + (size_t)b * HW_ + p;
        ((float4*)dp)[0] = make_float4(mx.x, 1.0f / s.x, mx.y, 1.0f / s.y);
        ((float4*)dp)[1] = make_float4(mx.z, 1.0f / s.z, mx.w, 1.0f / s.w);
        return;
    }

    // ---- vertical EDT branch: 2 adjacent columns per thread ----
    if (blockIdx.x == 0 && tid == 0) out[0] = 0.0f;   // replaces memset dispatch
    constexpr int SEG = 8, SH = 32;
    int s  = tid >> 5;          // segment
    int wl = tid & 31;          // column-pair within tile
    int blk = blockIdx.x;       // 96*4
    int bc = blk >> 2;
    int w0 = (blk & 3) * 64;
    int b = bc / C_, c = bc - b * C_;
    int w = w0 + 2 * wl;        // even
    const int* base = t + b * HW_ + w;
    int h0 = s * SH;

    unsigned tp0[SH / 4], tp1[SH / 4];
    int le0 = -1, ln0 = -1, fe0 = 256, fn0 = 256;
    int le1 = -1, ln1 = -1, fe1 = 256, fn1 = 256;
    #pragma unroll
    for (int i = 0; i < SH; ++i) {
        int2 tv = *(const int2*)(base + (h0 + i) * W_);
        if ((i & 3) == 0) { tp0[i >> 2] = 0; tp1[i >> 2] = 0; }
        tp0[i >> 2] |= (unsigned)tv.x << ((i & 3) * 8);
        tp1[i >> 2] |= (unsigned)tv.y << ((i & 3) * 8);
        int h = h0 + i;
        if (tv.x == c) { le0 = h; if (fe0 == 256) fe0 = h; }
        else           { ln0 = h; if (fn0 == 256) fn0 = h; }
        if (tv.y == c) { le1 = h; if (fe1 == 256) fe1 = h; }
        else           { ln1 = h; if (fn1 == 256) fn1 = h; }
    }
    __shared__ int sLE[SEG][64], sLN[SEG][64], sFE[SEG][64], sFN[SEG][64];
    sLE[s][2 * wl] = le0; sLE[s][2 * wl + 1] = le1;
    sLN[s][2 * wl] = ln0; sLN[s][2 * wl + 1] = ln1;
    sFE[s][2 * wl] = fe0; sFE[s][2 * wl + 1] = fe1;
    sFN[s][2 * wl] = fn0; sFN[s][2 * wl + 1] = fn1;
    __syncthreads();

    int carLE0 = -1, carLN0 = -1, carLE1 = -1, carLN1 = -1;
    for (int q = 0; q < s; ++q) {
        carLE0 = max(carLE0, sLE[q][2 * wl]);
        carLN0 = max(carLN0, sLN[q][2 * wl]);
        carLE1 = max(carLE1, sLE[q][2 * wl + 1]);
        carLN1 = max(carLN1, sLN[q][2 * wl + 1]);
    }
    int carFE0 = 256, carFN0 = 256, carFE1 = 256, carFN1 = 256;
    for (int q = s + 1; q < SEG; ++q) {
        carFE0 = min(carFE0, sFE[q][2 * wl]);
        carFN0 = min(carFN0, sFN[q][2 * wl]);
        carFE1 = min(carFE1, sFE[q][2 * wl + 1]);
        carFN1 = min(carFN1, sFN[q][2 * wl + 1]);
    }

    // tile has-fg: wave 0, column = tid (64 columns)
    bool pred = false;
    if (tid < 64) {
        int m = -1;
        #pragma unroll
        for (int q = 0; q < SEG; ++q) m = max(m, sLE[q][tid]);
        pred = (m >= 0);
    }
    bool anyfg = __any(pred);
    if (tid == 0) hasfg_p[blk] = anyfg ? 1 : 0;

    // forward pass: u8-encode dl-1 (255 = no zero at-or-above)
    unsigned ap0[SH / 4], ap1[SH / 4];
    {
        int l0 = carLE0, n0 = carLN0, l1 = carLE1, n1 = carLN1;
        #pragma unroll
        for (int i = 0; i < SH; ++i) {
            int h = h0 + i;
            int tv0 = (tp0[i >> 2] >> ((i & 3) * 8)) & 0xFF;
            int tv1 = (tp1[i >> 2] >> ((i & 3) * 8)) & 0xFF;
            int lz0, lz1;
            if (tv0 == c) { l0 = h; lz0 = n0; } else { n0 = h; lz0 = l0; }
            if (tv1 == c) { l1 = h; lz1 = n1; } else { n1 = h; lz1 = l1; }
            unsigned a0 = (lz0 < 0) ? 255u : (unsigned)(h - lz0 - 1);
            unsigned a1 = (lz1 < 0) ? 255u : (unsigned)(h - lz1 - 1);
            if ((i & 3) == 0) { ap0[i >> 2] = 0; ap1[i >> 2] = 0; }
            ap0[i >> 2] |= a0 << ((i & 3) * 8);
            ap1[i >> 2] |= a1 << ((i & 3) * 8);
        }
    }
    // backward pass: d = min(dl, dn), packed u32 store (2 cols)
    {
        int fe0_ = carFE0, fn0_ = carFN0, fe1_ = carFE1, fn1_ = carFN1;
        unsigned* gk32 = (unsigned*)(gpk + (size_t)bc * HW_ + w);
        #pragma unroll
        for (int i = SH - 1; i >= 0; --i) {
            int h = h0 + i;
            int tv0 = (tp0[i >> 2] >> ((i & 3) * 8)) & 0xFF;
            int tv1 = (tp1[i >> 2] >> ((i & 3) * 8)) & 0xFF;
            int nz0, nz1; bool fg0, fg1;
            if (tv0 == c) { fe0_ = h; fg0 = true;  nz0 = fn0_; }
            else          { fn0_ = h; fg0 = false; nz0 = fe0_; }
            if (tv1 == c) { fe1_ = h; fg1 = true;  nz1 = fn1_; }
            else          { fn1_ = h; fg1 = false; nz1 = fe1_; }
            unsigned au0 = (ap0[i >> 2] >> ((i & 3) * 8)) & 0xFF;
            unsigned au1 = (ap1[i >> 2] >> ((i & 3) * 8)) & 0xFF;
            int dl0 = (au0 == 255u) ? 0x7FFF : (int)au0 + 1;
            int dl1 = (au1 == 255u) ? 0x7FFF : (int)au1 + 1;
            int dn0 = (nz0 > 255) ? 0x7FFF : (nz0 - h);
            int dn1 = (nz1 > 255) ? 0x7FFF : (nz1 - h);
            unsigned d0 = (unsigned)min(dl0, dn0) | (fg0 ? 0x8000u : 0u);
            unsigned d1 = (unsigned)min(dl1, dn1) | (fg1 ? 0x8000u : 0u);
            gk32[(h * W_) >> 1] = d0 | (d1 << 16);
        }
    }
}

// ---------------------------------------------------------------------------
// K2 (fused): per-row horizontal EDT + own-class prob + raw dice sums.
// One wave per (bc,h) row; 4 rows (same bc) per block; no dt materialized.
// LDS: 258-wide rows (data 0..255, +inf cells @256,257) instead of 256-wide
// inf pads on both sides -> 8.4KB/block (was 24.5KB) -> 8 blocks/CU = 32
// waves/CU (was 24). Scan reads use clamped indices:
//   jm = min((unsigned)(j-r), 257)  (negative wraps to inf cell 257)
//   jp = min(j+r, 256)              (overflow hits inf cell 256)
// fminf(inf, x) == pad semantics -> bit-identical results.
// ---------------------------------------------------------------------------
__global__ void __launch_bounds__(256) k_edt(
                      const unsigned short* __restrict__ gpk,
                      const float* __restrict__ logits,
                      const float2* __restrict__ den,
                      const int* __restrict__ hasfg_p,
                      float* __restrict__ part) {
    __shared__ float sp[4][LROW_];
    __shared__ float sn[4][LROW_];
    int wave = threadIdx.x >> 6;
    int lane = threadIdx.x & 63;
    int row = blockIdx.x * 4 + wave;       // bc*256 + h; all 4 rows same bc
    int bc = row >> 8;
    int b = bc / C_, c = bc - b * C_;
    int h = row & (H_ - 1);

    int hfl = 0;
    if (lane < 4) hfl = hasfg_p[bc * 4 + lane];
    bool hf = __any(hfl != 0);             // uniform across block (same bc)

    // hoist independent prob-path loads: latency hides under the EDT scans
    const float*  lrow = logits + ((size_t)b * C_ + c) * HW_ + h * W_;
    const float2* drow = den + (size_t)b * HW_ + h * W_;
    float lv[4]; float2 mv[4];
    #pragma unroll
    for (int i = 0; i < 4; ++i) {
        int j = lane + 64 * i;
        lv[i] = lrow[j];
        mv[i] = drow[j];
    }

    float dv[4];
    if (hf) {
        const ushort4 v4 = ((const ushort4*)(gpk + (size_t)row * W_))[lane];

        // inf cells (written once; never overwritten by row data)
        if (lane < 2) {
            sp[wave][256 + lane] = 3.0e38f;
            sn[wave][256 + lane] = 3.0e38f;
        }

        float s1 = (float)(1000000 - h);
        float sent2 = s1 * s1;             // == fl((1e6 - h)^2), reference-exact
        float4 fpv, fnv;
        {
            const unsigned short* vs = (const unsigned short*)&v4;
            float* fp = (float*)&fpv;
            float* fn = (float*)&fnv;
            #pragma unroll
            for (int q = 0; q < 4; ++q) {
                unsigned v = vs[q];
                unsigned d = v & 0x7FFFu;
                float g2 = (d == 0x7FFFu) ? sent2 : (float)(d * d);
                bool fg = (v & 0x8000u) != 0;
                fp[q] = fg ? g2 : 0.0f;
                fn[q] = fg ? 0.0f : g2;
            }
        }
        ((float4*)&sp[wave][0])[lane] = fpv;   // pixel 4*lane..4*lane+3
        ((float4*)&sn[wave][0])[lane] = fnv;
        // wave-private LDS rows: wave-local wait suffices (no barrier)
        asm volatile("s_waitcnt lgkmcnt(0)" ::: "memory");

        float bp[4], bn[4];
        #pragma unroll
        for (int i = 0; i < 4; ++i) {
            int j = lane + 64 * i;
            bp[i] = sp[wave][j];
            bn[i] = sn[wave][j];
        }
        for (int r = 1; r < W_; ++r) {
            float fr = (float)r;
            float r2 = fr * fr;
            float m = fmaxf(fmaxf(bn[0], bn[1]), fmaxf(bn[2], bn[3]));
            if (!__any(r2 < m)) break;
            #pragma unroll
            for (int i = 0; i < 4; ++i) {
                int j = lane + 64 * i;
                int jm = (int)min((unsigned)(j - r), 257u);
                int jp = min(j + r, 256);
                float v = fminf(sn[wave][jm], sn[wave][jp]);
                bn[i] = fminf(bn[i], fmaf(fr, fr, v));
            }
        }
        for (int r = 1; r < W_; ++r) {
            float fr = (float)r;
            float r2 = fr * fr;
            float m = fmaxf(fmaxf(bp[0], bp[1]), fmaxf(bp[2], bp[3]));
            if (!__any(r2 < m)) break;
            #pragma unroll
            for (int i = 0; i < 4; ++i) {
                int j = lane + 64 * i;
                int jm = (int)min((unsigned)(j - r), 257u);
                int jp = min(j + r, 256);
                float v = fminf(sp[wave][jm], sp[wave][jp]);
                bp[i] = fminf(bp[i], fmaf(fr, fr, v));
            }
        }
        #pragma unroll
        for (int i = 0; i < 4; ++i) dv[i] = sqrtf(bn[i]) - sqrtf(bp[i]);
    } else {
        #pragma unroll
        for (int i = 0; i < 4; ++i) dv[i] = 0.0f;
    }

    // own-class prob from precomputed stats + raw sums over 256 pixels
    float s_pd = 0.f, s_p = 0.f, s_pp = 0.f, s_d = 0.f, s_dd = 0.f;
    float mn = 3.4e38f, mx = -3.4e38f;
    #pragma unroll
    for (int i = 0; i < 4; ++i) {
        float2 mi = mv[i];
        float pr = __expf(lv[i] - mi.x) * mi.y;
        float d = dv[i];
        s_pd = fmaf(pr, d, s_pd);
        s_p += pr;
        s_pp = fmaf(pr, pr, s_pp);
        s_d += d;
        s_dd = fmaf(d, d, s_dd);
        mn = fminf(mn, d);
        mx = fmaxf(mx, d);
    }
    #pragma unroll
    for (int off = 32; off; off >>= 1) {
        s_pd += __shfl_down(s_pd, off);
        s_p  += __shfl_down(s_p, off);
        s_pp += __shfl_down(s_pp, off);
        s_d  += __shfl_down(s_d, off);
        s_dd += __shfl_down(s_dd, off);
        mn = fminf(mn, __shfl_down(mn, off));
        mx = fmaxf(mx, __shfl_down(mx, off));
    }
    if (lane == 0) {
        float* p8 = part + (size_t)row * 8;
        p8[0] = s_pd; p8[1] = s_p; p8[2] = s_pp;
        p8[3] = s_d;  p8[4] = s_dd; p8[5] = mn; p8[6] = mx;
    }
}

// ---------------------------------------------------------------------------
// K3: per-(b,c) reduce of 256 row partials -> dice -> atomicAdd loss term.
// out[0] zeroed by k_vp block 0. inter = sc*(S_pd - mn*S_p);
// d2 = sc^2*(S_dd - 2 mn S_d + mn^2 N). 96 atomics total.
// ---------------------------------------------------------------------------
__global__ void __launch_bounds__(256) k_bcred(
                       const float* __restrict__ part, float* __restrict__ out) {
    int bc = blockIdx.x;
    int tid = threadIdx.x;                 // 256
    const float* p8 = part + ((size_t)bc * 256 + tid) * 8;
    float s_pd = p8[0], s_p = p8[1], s_pp = p8[2];
    float s_d = p8[3], s_dd = p8[4], mn = p8[5], mx = p8[6];
    #pragma unroll
    for (int off = 32; off; off >>= 1) {
        s_pd += __shfl_down(s_pd, off);
        s_p  += __shfl_down(s_p, off);
        s_pp += __shfl_down(s_pp, off);
        s_d  += __shfl_down(s_d, off);
        s_dd += __shfl_down(s_dd, off);
        mn = fminf(mn, __shfl_down(mn, off));
        mx = fmaxf(mx, __shfl_down(mx, off));
    }
    __shared__ float red[4][7];
    int wave = tid >> 6, lane = tid & 63;
    if (lane == 0) {
        red[wave][0] = s_pd; red[wave][1] = s_p; red[wave][2] = s_pp;
        red[wave][3] = s_d;  red[wave][4] = s_dd; red[wave][5] = mn; red[wave][6] = mx;
    }
    __syncthreads();
    if (tid == 0) {
        s_pd = red[0][0]; s_p = red[0][1]; s_pp = red[0][2];
        s_d = red[0][3]; s_dd = red[0][4]; mn = red[0][5]; mx = red[0][6];
        for (int w = 1; w < 4; ++w) {
            s_pd += red[w][0]; s_p += red[w][1]; s_pp += red[w][2];
            s_d += red[w][3]; s_dd += red[w][4];
            mn = fminf(mn, red[w][5]); mx = fmaxf(mx, red[w][6]);
        }
        float sc = 1.0f / (mx - mn + 1e-8f);
        float inter = sc * (s_pd - mn * s_p);
        float d2 = sc * sc * (s_dd - 2.0f * mn * s_d + mn * mn * (float)HW_);
        float dice = 2.0f * inter / (s_pp + d2 + 1e-6f);
        atomicAdd(out, (1.0f - dice) * (1.0f / (float)NBC_));
    }
}

// ---------------------------------------------------------------------------
extern "C" void kernel_launch(void* const* d_in, const int* in_sizes, int n_in,
                              void* d_out, int out_size, void* d_ws, size_t ws_size,
                              hipStream_t stream) {
    const float* logits  = (const float*)d_in[0];
    const int*   targets = (const int*)d_in[1];
    float* out = (float*)d_out;

    // ws layout: gpk u16[96*65536] | hasfg_p i32[768] | part f32[24576*8] |
    //            den float2[8*65536]
    unsigned short* gpk = (unsigned short*)d_ws;
    int* hasfg_p = (int*)(gpk + (size_t)NBC_ * HW_);
    float* part = (float*)(hasfg_p + NBC_ * 8);
    float2* den = (float2*)(part + (size_t)NBC_ * H_ * 8);

    k_vp<<<VB_ + SMB_, 256, 0, stream>>>(targets, logits, gpk,
                                         hasfg_p, den, out);
    k_edt<<<NBC_ * H_ / 4, 256, 0, stream>>>(gpk, logits, den, hasfg_p, part);
    k_bcred<<<NBC_, 256, 0, stream>>>(part, out);
}

// Round 7
// 110.341 us; speedup vs baseline: 5.3905x; 1.0161x over previous
//
#include <hip/hip_runtime.h>
#include <math.h>

// Problem shape (fixed by setup_inputs): logits [8,12,256,256] fp32, targets [8,256,256] i32.
constexpr int B_  = 8;
constexpr int C_  = 12;
constexpr int H_  = 256;
constexpr int W_  = 256;
constexpr int HW_ = H_ * W_;
constexpr int NBC_ = B_ * C_;           // 96
constexpr int VB_  = NBC_ * 4;          // vert tiles (384): 64 columns per tile
constexpr int SMB_ = B_ * (HW_ / 1024); // softmax-stats blocks (512, 4 px/thread)
constexpr int PADL_ = 128;              // LDS pad: covers r<=128 affine reads
constexpr int LROW_ = PADL_ + W_ + PADL_;  // 512 floats per LDS row

// Packed vertical-EDT value: bit15 = is_fg (t==c); bits[14:0] = vertical
// distance d to nearest zero of the pixel's own nonzero transform
// (0x7FFF = no zero in column -> reference g = 1e6 - h). The OTHER
// transform's g is always 0 at this pixel, so one u16 encodes both.

// ---------------------------------------------------------------------------
// K1 (merged): blocks [0,384) = vertical EDT scans (64 cols x 8 segments,
// 2 adjacent columns per thread -> int2 loads, packed u32 stores);
// blocks [384, 384+512) = per-pixel softmax stats den = {max, 1/sum},
// float4 (4 px/thread). Block 0 zeroes out[0] (consumed by k_bcred).
// ---------------------------------------------------------------------------
__global__ void __launch_bounds__(256) k_vp(
                     const int* __restrict__ t,
                     const float* __restrict__ logits,
                     unsigned short* __restrict__ gpk,
                     int* __restrict__ hasfg_p,
                     float2* __restrict__ den,
                     float* __restrict__ out) {
    int tid = threadIdx.x;
    if (blockIdx.x >= VB_) {
        // ---- softmax-stats branch (float4: 4 pixels per thread) ----
        int pb = blockIdx.x - VB_;             // [0, 512)
        int b = pb >> 6;
        int p = ((pb & 63) << 10) + tid * 4;
        const float* lb = logits + (size_t)b * C_ * HW_ + p;
        float4 l[C_];
        float4 mx = make_float4(-3.4e38f, -3.4e38f, -3.4e38f, -3.4e38f);
        #pragma unroll
        for (int c = 0; c < C_; ++c) {
            l[c] = *(const float4*)(lb + (size_t)c * HW_);
            mx.x = fmaxf(mx.x, l[c].x);
            mx.y = fmaxf(mx.y, l[c].y);
            mx.z = fmaxf(mx.z, l[c].z);
            mx.w = fmaxf(mx.w, l[c].w);
        }
        float4 s = make_float4(0.f, 0.f, 0.f, 0.f);
        #pragma unroll
        for (int c = 0; c < C_; ++c) {
            s.x += __expf(l[c].x - mx.x);
            s.y += __expf(l[c].y - mx.y);
            s.z += __expf(l[c].z - mx.z);
            s.w += __expf(l[c].w - mx.w);
        }
        float2* dp = den + (size_t)b * HW_ + p;
        ((float4*)dp)[0] = make_float4(mx.x, 1.0f / s.x, mx.y, 1.0f / s.y);
        ((float4*)dp)[1] = make_float4(mx.z, 1.0f / s.z, mx.w, 1.0f / s.w);
        return;
    }

    // ---- vertical EDT branch: 2 adjacent columns per thread ----
    if (blockIdx.x == 0 && tid == 0) out[0] = 0.0f;   // replaces memset dispatch
    constexpr int SEG = 8, SH = 32;
    int s  = tid >> 5;          // segment
    int wl = tid & 31;          // column-pair within tile
    int blk = blockIdx.x;       // 96*4
    int bc = blk >> 2;
    int w0 = (blk & 3) * 64;
    int b = bc / C_, c = bc - b * C_;
    int w = w0 + 2 * wl;        // even
    const int* base = t + b * HW_ + w;
    int h0 = s * SH;

    unsigned tp0[SH / 4], tp1[SH / 4];
    int le0 = -1, ln0 = -1, fe0 = 256, fn0 = 256;
    int le1 = -1, ln1 = -1, fe1 = 256, fn1 = 256;
    #pragma unroll
    for (int i = 0; i < SH; ++i) {
        int2 tv = *(const int2*)(base + (h0 + i) * W_);
        if ((i & 3) == 0) { tp0[i >> 2] = 0; tp1[i >> 2] = 0; }
        tp0[i >> 2] |= (unsigned)tv.x << ((i & 3) * 8);
        tp1[i >> 2] |= (unsigned)tv.y << ((i & 3) * 8);
        int h = h0 + i;
        if (tv.x == c) { le0 = h; if (fe0 == 256) fe0 = h; }
        else           { ln0 = h; if (fn0 == 256) fn0 = h; }
        if (tv.y == c) { le1 = h; if (fe1 == 256) fe1 = h; }
        else           { ln1 = h; if (fn1 == 256) fn1 = h; }
    }
    __shared__ int sLE[SEG][64], sLN[SEG][64], sFE[SEG][64], sFN[SEG][64];
    sLE[s][2 * wl] = le0; sLE[s][2 * wl + 1] = le1;
    sLN[s][2 * wl] = ln0; sLN[s][2 * wl + 1] = ln1;
    sFE[s][2 * wl] = fe0; sFE[s][2 * wl + 1] = fe1;
    sFN[s][2 * wl] = fn0; sFN[s][2 * wl + 1] = fn1;
    __syncthreads();

    int carLE0 = -1, carLN0 = -1, carLE1 = -1, carLN1 = -1;
    for (int q = 0; q < s; ++q) {
        carLE0 = max(carLE0, sLE[q][2 * wl]);
        carLN0 = max(carLN0, sLN[q][2 * wl]);
        carLE1 = max(carLE1, sLE[q][2 * wl + 1]);
        carLN1 = max(carLN1, sLN[q][2 * wl + 1]);
    }
    int carFE0 = 256, carFN0 = 256, carFE1 = 256, carFN1 = 256;
    for (int q = s + 1; q < SEG; ++q) {
        carFE0 = min(carFE0, sFE[q][2 * wl]);
        carFN0 = min(carFN0, sFN[q][2 * wl]);
        carFE1 = min(carFE1, sFE[q][2 * wl + 1]);
        carFN1 = min(carFN1, sFN[q][2 * wl + 1]);
    }

    // tile has-fg: wave 0, column = tid (64 columns)
    bool pred = false;
    if (tid < 64) {
        int m = -1;
        #pragma unroll
        for (int q = 0; q < SEG; ++q) m = max(m, sLE[q][tid]);
        pred = (m >= 0);
    }
    bool anyfg = __any(pred);
    if (tid == 0) hasfg_p[blk] = anyfg ? 1 : 0;

    // forward pass: u8-encode dl-1 (255 = no zero at-or-above)
    unsigned ap0[SH / 4], ap1[SH / 4];
    {
        int l0 = carLE0, n0 = carLN0, l1 = carLE1, n1 = carLN1;
        #pragma unroll
        for (int i = 0; i < SH; ++i) {
            int h = h0 + i;
            int tv0 = (tp0[i >> 2] >> ((i & 3) * 8)) & 0xFF;
            int tv1 = (tp1[i >> 2] >> ((i & 3) * 8)) & 0xFF;
            int lz0, lz1;
            if (tv0 == c) { l0 = h; lz0 = n0; } else { n0 = h; lz0 = l0; }
            if (tv1 == c) { l1 = h; lz1 = n1; } else { n1 = h; lz1 = l1; }
            unsigned a0 = (lz0 < 0) ? 255u : (unsigned)(h - lz0 - 1);
            unsigned a1 = (lz1 < 0) ? 255u : (unsigned)(h - lz1 - 1);
            if ((i & 3) == 0) { ap0[i >> 2] = 0; ap1[i >> 2] = 0; }
            ap0[i >> 2] |= a0 << ((i & 3) * 8);
            ap1[i >> 2] |= a1 << ((i & 3) * 8);
        }
    }
    // backward pass: d = min(dl, dn), packed u32 store (2 cols)
    {
        int fe0_ = carFE0, fn0_ = carFN0, fe1_ = carFE1, fn1_ = carFN1;
        unsigned* gk32 = (unsigned*)(gpk + (size_t)bc * HW_ + w);
        #pragma unroll
        for (int i = SH - 1; i >= 0; --i) {
            int h = h0 + i;
            int tv0 = (tp0[i >> 2] >> ((i & 3) * 8)) & 0xFF;
            int tv1 = (tp1[i >> 2] >> ((i & 3) * 8)) & 0xFF;
            int nz0, nz1; bool fg0, fg1;
            if (tv0 == c) { fe0_ = h; fg0 = true;  nz0 = fn0_; }
            else          { fn0_ = h; fg0 = false; nz0 = fe0_; }
            if (tv1 == c) { fe1_ = h; fg1 = true;  nz1 = fn1_; }
            else          { fn1_ = h; fg1 = false; nz1 = fe1_; }
            unsigned au0 = (ap0[i >> 2] >> ((i & 3) * 8)) & 0xFF;
            unsigned au1 = (ap1[i >> 2] >> ((i & 3) * 8)) & 0xFF;
            int dl0 = (au0 == 255u) ? 0x7FFF : (int)au0 + 1;
            int dl1 = (au1 == 255u) ? 0x7FFF : (int)au1 + 1;
            int dn0 = (nz0 > 255) ? 0x7FFF : (nz0 - h);
            int dn1 = (nz1 > 255) ? 0x7FFF : (nz1 - h);
            unsigned d0 = (unsigned)min(dl0, dn0) | (fg0 ? 0x8000u : 0u);
            unsigned d1 = (unsigned)min(dl1, dn1) | (fg1 ? 0x8000u : 0u);
            gk32[(h * W_) >> 1] = d0 | (d1 << 16);
        }
    }
}

// ---------------------------------------------------------------------------
// K2 (fused): per-row horizontal EDT + own-class prob + raw dice sums.
// One wave per (bc,h) row; 4 rows (same bc) per block; no dt materialized.
// LDS: 128-float inf pads both sides (16.4KB/block -> 8 blocks/CU wave cap).
// Two-phase scan: r<=128 uses AFFINE reads s[PADL+lane+64i +/- r] (in-bounds
// by construction; compiler merges into ds_read2_b32) -- the hot path.
// r>128 (rare: near-empty classes) uses index-clamped reads into the inf
// pads. Identical r-sequence & update order -> bit-identical to R1.
// ---------------------------------------------------------------------------
__global__ void __launch_bounds__(256) k_edt(
                      const unsigned short* __restrict__ gpk,
                      const float* __restrict__ logits,
                      const float2* __restrict__ den,
                      const int* __restrict__ hasfg_p,
                      float* __restrict__ part) {
    __shared__ float sp[4][LROW_];
    __shared__ float sn[4][LROW_];
    int wave = threadIdx.x >> 6;
    int lane = threadIdx.x & 63;
    int row = blockIdx.x * 4 + wave;       // bc*256 + h; all 4 rows same bc
    int bc = row >> 8;
    int b = bc / C_, c = bc - b * C_;
    int h = row & (H_ - 1);

    int hfl = 0;
    if (lane < 4) hfl = hasfg_p[bc * 4 + lane];
    bool hf = __any(hfl != 0);             // uniform across block (same bc)

    // hoist independent prob-path loads: latency hides under the EDT scans
    const float*  lrow = logits + ((size_t)b * C_ + c) * HW_ + h * W_;
    const float2* drow = den + (size_t)b * HW_ + h * W_;
    float lv[4]; float2 mv[4];
    #pragma unroll
    for (int i = 0; i < 4; ++i) {
        int j = lane + 64 * i;
        lv[i] = lrow[j];
        mv[i] = drow[j];
    }

    float dv[4];
    if (hf) {
        const ushort4 v4 = ((const ushort4*)(gpk + (size_t)row * W_))[lane];

        // pad init: left pad = float4 slots [0,32), right pad = slots [96,128)
        float4 inf4 = make_float4(3.0e38f, 3.0e38f, 3.0e38f, 3.0e38f);
        int slot = (lane < 32) ? lane : (lane + 64);
        ((float4*)&sp[wave][0])[slot] = inf4;
        ((float4*)&sn[wave][0])[slot] = inf4;

        float s1 = (float)(1000000 - h);
        float sent2 = s1 * s1;             // == fl((1e6 - h)^2), reference-exact
        float4 fpv, fnv;
        {
            const unsigned short* vs = (const unsigned short*)&v4;
            float* fp = (float*)&fpv;
            float* fn = (float*)&fnv;
            #pragma unroll
            for (int q = 0; q < 4; ++q) {
                unsigned v = vs[q];
                unsigned d = v & 0x7FFFu;
                float g2 = (d == 0x7FFFu) ? sent2 : (float)(d * d);
                bool fg = (v & 0x8000u) != 0;
                fp[q] = fg ? g2 : 0.0f;
                fn[q] = fg ? 0.0f : g2;
            }
        }
        ((float4*)&sp[wave][PADL_])[lane] = fpv;   // data at [128, 384)
        ((float4*)&sn[wave][PADL_])[lane] = fnv;
        // wave-private LDS rows: wave-local wait suffices (no barrier)
        asm volatile("s_waitcnt lgkmcnt(0)" ::: "memory");

        float bp[4], bn[4];
        #pragma unroll
        for (int i = 0; i < 4; ++i) {
            int j = PADL_ + lane + 64 * i;
            bp[i] = sp[wave][j];
            bn[i] = sn[wave][j];
        }
        // ---- neg transform scan ----
        {
            bool doneN = false;
            int r = 1;
            for (; r <= PADL_; ++r) {          // affine fast path (ds_read2)
                float fr = (float)r;
                float r2 = fr * fr;
                float m = fmaxf(fmaxf(bn[0], bn[1]), fmaxf(bn[2], bn[3]));
                if (!__any(r2 < m)) { doneN = true; break; }
                #pragma unroll
                for (int i = 0; i < 4; ++i) {
                    int j = PADL_ + lane + 64 * i;
                    float v = fminf(sn[wave][j - r], sn[wave][j + r]);
                    bn[i] = fminf(bn[i], fmaf(fr, fr, v));
                }
            }
            if (!doneN) {
                for (; r < W_; ++r) {          // rare tail: clamped reads
                    float fr = (float)r;
                    float r2 = fr * fr;
                    float m = fmaxf(fmaxf(bn[0], bn[1]), fmaxf(bn[2], bn[3]));
                    if (!__any(r2 < m)) break;
                    #pragma unroll
                    for (int i = 0; i < 4; ++i) {
                        int j = PADL_ + lane + 64 * i;
                        int jm = max(j - r, 0);
                        int jp = min(j + r, LROW_ - 1);
                        float v = fminf(sn[wave][jm], sn[wave][jp]);
                        bn[i] = fminf(bn[i], fmaf(fr, fr, v));
                    }
                }
            }
        }
        // ---- pos transform scan ----
        {
            bool doneP = false;
            int r = 1;
            for (; r <= PADL_; ++r) {          // affine fast path (ds_read2)
                float fr = (float)r;
                float r2 = fr * fr;
                float m = fmaxf(fmaxf(bp[0], bp[1]), fmaxf(bp[2], bp[3]));
                if (!__any(r2 < m)) { doneP = true; break; }
                #pragma unroll
                for (int i = 0; i < 4; ++i) {
                    int j = PADL_ + lane + 64 * i;
                    float v = fminf(sp[wave][j - r], sp[wave][j + r]);
                    bp[i] = fminf(bp[i], fmaf(fr, fr, v));
                }
            }
            if (!doneP) {
                for (; r < W_; ++r) {          // rare tail: clamped reads
                    float fr = (float)r;
                    float r2 = fr * fr;
                    float m = fmaxf(fmaxf(bp[0], bp[1]), fmaxf(bp[2], bp[3]));
                    if (!__any(r2 < m)) break;
                    #pragma unroll
                    for (int i = 0; i < 4; ++i) {
                        int j = PADL_ + lane + 64 * i;
                        int jm = max(j - r, 0);
                        int jp = min(j + r, LROW_ - 1);
                        float v = fminf(sp[wave][jm], sp[wave][jp]);
                        bp[i] = fminf(bp[i], fmaf(fr, fr, v));
                    }
                }
            }
        }
        #pragma unroll
        for (int i = 0; i < 4; ++i) dv[i] = sqrtf(bn[i]) - sqrtf(bp[i]);
    } else {
        #pragma unroll
        for (int i = 0; i < 4; ++i) dv[i] = 0.0f;
    }

    // own-class prob from precomputed stats + raw sums over 256 pixels
    float s_pd = 0.f, s_p = 0.f, s_pp = 0.f, s_d = 0.f, s_dd = 0.f;
    float mn = 3.4e38f, mx = -3.4e38f;
    #pragma unroll
    for (int i = 0; i < 4; ++i) {
        float2 mi = mv[i];
        float pr = __expf(lv[i] - mi.x) * mi.y;
        float d = dv[i];
        s_pd = fmaf(pr, d, s_pd);
        s_p += pr;
        s_pp = fmaf(pr, pr, s_pp);
        s_d += d;
        s_dd = fmaf(d, d, s_dd);
        mn = fminf(mn, d);
        mx = fmaxf(mx, d);
    }
    #pragma unroll
    for (int off = 32; off; off >>= 1) {
        s_pd += __shfl_down(s_pd, off);
        s_p  += __shfl_down(s_p, off);
        s_pp += __shfl_down(s_pp, off);
        s_d  += __shfl_down(s_d, off);
        s_dd += __shfl_down(s_dd, off);
        mn = fminf(mn, __shfl_down(mn, off));
        mx = fmaxf(mx, __shfl_down(mx, off));
    }
    if (lane == 0) {
        float4* p4 = (float4*)(part + (size_t)row * 8);   // 32B-aligned
        p4[0] = make_float4(s_pd, s_p, s_pp, s_d);
        p4[1] = make_float4(s_dd, mn, mx, 0.0f);
    }
}

// ---------------------------------------------------------------------------
// K3: per-(b,c) reduce of 256 row partials -> dice -> atomicAdd loss term.
// out[0] zeroed by k_vp block 0. inter = sc*(S_pd - mn*S_p);
// d2 = sc^2*(S_dd - 2 mn S_d + mn^2 N). 96 atomics total.
// ---------------------------------------------------------------------------
__global__ void __launch_bounds__(256) k_bcred(
                       const float* __restrict__ part, float* __restrict__ out) {
    int bc = blockIdx.x;
    int tid = threadIdx.x;                 // 256
    const float4* p4 = (const float4*)(part + ((size_t)bc * 256 + tid) * 8);
    float4 a = p4[0], bq = p4[1];
    float s_pd = a.x, s_p = a.y, s_pp = a.z;
    float s_d = a.w, s_dd = bq.x, mn = bq.y, mx = bq.z;
    #pragma unroll
    for (int off = 32; off; off >>= 1) {
        s_pd += __shfl_down(s_pd, off);
        s_p  += __shfl_down(s_p, off);
        s_pp += __shfl_down(s_pp, off);
        s_d  += __shfl_down(s_d, off);
        s_dd += __shfl_down(s_dd, off);
        mn = fminf(mn, __shfl_down(mn, off));
        mx = fmaxf(mx, __shfl_down(mx, off));
    }
    __shared__ float red[4][7];
    int wave = tid >> 6, lane = tid & 63;
    if (lane == 0) {
        red[wave][0] = s_pd; red[wave][1] = s_p; red[wave][2] = s_pp;
        red[wave][3] = s_d;  red[wave][4] = s_dd; red[wave][5] = mn; red[wave][6] = mx;
    }
    __syncthreads();
    if (tid == 0) {
        s_pd = red[0][0]; s_p = red[0][1]; s_pp = red[0][2];
        s_d = red[0][3]; s_dd = red[0][4]; mn = red[0][5]; mx = red[0][6];
        for (int w = 1; w < 4; ++w) {
            s_pd += red[w][0]; s_p += red[w][1]; s_pp += red[w][2];
            s_d += red[w][3]; s_dd += red[w][4];
            mn = fminf(mn, red[w][5]); mx = fmaxf(mx, red[w][6]);
        }
        float sc = 1.0f / (mx - mn + 1e-8f);
        float inter = sc * (s_pd - mn * s_p);
        float d2 = sc * sc * (s_dd - 2.0f * mn * s_d + mn * mn * (float)HW_);
        float dice = 2.0f * inter / (s_pp + d2 + 1e-6f);
        atomicAdd(out, (1.0f - dice) * (1.0f / (float)NBC_));
    }
}

// ---------------------------------------------------------------------------
extern "C" void kernel_launch(void* const* d_in, const int* in_sizes, int n_in,
                              void* d_out, int out_size, void* d_ws, size_t ws_size,
                              hipStream_t stream) {
    const float* logits  = (const float*)d_in[0];
    const int*   targets = (const int*)d_in[1];
    float* out = (float*)d_out;

    // ws layout: gpk u16[96*65536] | hasfg_p i32[768] | part f32[24576*8] |
    //            den float2[8*65536]
    unsigned short* gpk = (unsigned short*)d_ws;
    int* hasfg_p = (int*)(gpk + (size_t)NBC_ * HW_);
    float* part = (float*)(hasfg_p + NBC_ * 8);
    float2* den = (float2*)(part + (size_t)NBC_ * H_ * 8);

    k_vp<<<VB_ + SMB_, 256, 0, stream>>>(targets, logits, gpk,
                                         hasfg_p, den, out);
    k_edt<<<NBC_ * H_ / 4, 256, 0, stream>>>(gpk, logits, den, hasfg_p, part);
    k_bcred<<<NBC_, 256, 0, stream>>>(part, out);
}

// Round 8
// 106.422 us; speedup vs baseline: 5.5890x; 1.0368x over previous
//
#include <hip/hip_runtime.h>
#include <math.h>

// Problem shape (fixed by setup_inputs): logits [8,12,256,256] fp32, targets [8,256,256] i32.
constexpr int B_  = 8;
constexpr int C_  = 12;
constexpr int H_  = 256;
constexpr int W_  = 256;
constexpr int HW_ = H_ * W_;
constexpr int NBC_ = B_ * C_;           // 96
constexpr int VB_  = NBC_ * 8;          // vert tiles (768): 32 columns per tile
constexpr int SMB_ = B_ * (HW_ / 512);  // softmax blocks (1024): 2 px/thread
constexpr int PADL_ = 128;              // LDS pad: covers r<=128 affine reads
constexpr int LROW_ = PADL_ + W_ + PADL_;  // 512 floats per LDS row

// Packed vertical-EDT value: bit15 = is_fg (t==c); bits[14:0] = vertical
// distance d to nearest zero of the pixel's own nonzero transform
// (0x7FFF = no zero in column -> reference g = 1e6 - h). The OTHER
// transform's g is always 0 at this pixel, so one u16 encodes both.

// ---------------------------------------------------------------------------
// K1a: vertical EDT. R7 counters showed the merged k_vp at 47us, 658 GB/s,
// VALUBusy 13.5%, Occ 15.8% -> latency-bound, too few waves, chains too long.
// Fix: 512-thr blocks, 16 segments x 16 rows x 1 col/thread -> 768 blocks =
// 6144 waves (4x R7) and 16-iter serial passes (half R7's 32).
// Block 0 zeroes out[0] (consumed by k_bcred, 3 dispatches later).
// ---------------------------------------------------------------------------
__global__ void __launch_bounds__(512) k_vert(
                     const int* __restrict__ t,
                     unsigned short* __restrict__ gpk,
                     int* __restrict__ hasfg_p,
                     float* __restrict__ out) {
    int tid = threadIdx.x;
    if (blockIdx.x == 0 && tid == 0) out[0] = 0.0f;   // replaces memset dispatch
    constexpr int SEG = 16, SH = 16;
    int s  = tid >> 5;          // segment 0..15
    int wl = tid & 31;          // column within tile
    int blk = blockIdx.x;       // 96*8
    int bc = blk >> 3;
    int w0 = (blk & 7) * 32;
    int b = bc / C_, c = bc - b * C_;
    int w = w0 + wl;
    const int* base = t + b * HW_ + w;
    int h0 = s * SH;

    unsigned tp[SH / 4];        // 4 regs: u8-packed targets for this segment
    int lastEq = -1, lastNeq = -1, firstEq = 256, firstNeq = 256;
    #pragma unroll
    for (int i = 0; i < SH; ++i) {
        int tv = base[(h0 + i) * W_];
        if ((i & 3) == 0) tp[i >> 2] = 0;
        tp[i >> 2] |= (unsigned)tv << ((i & 3) * 8);
        int h = h0 + i;
        if (tv == c) { lastEq = h;  if (firstEq  == 256) firstEq  = h; }
        else         { lastNeq = h; if (firstNeq == 256) firstNeq = h; }
    }
    __shared__ int sLE[SEG][32], sLN[SEG][32], sFE[SEG][32], sFN[SEG][32];
    sLE[s][wl] = lastEq; sLN[s][wl] = lastNeq;
    sFE[s][wl] = firstEq; sFN[s][wl] = firstNeq;
    __syncthreads();

    int carLE = -1, carLN = -1;
    for (int q = 0; q < s; ++q) {
        carLE = max(carLE, sLE[q][wl]);
        carLN = max(carLN, sLN[q][wl]);
    }
    int carFE = 256, carFN = 256;
    for (int q = s + 1; q < SEG; ++q) {
        carFE = min(carFE, sFE[q][wl]);
        carFN = min(carFN, sFN[q][wl]);
    }

    // tile has-fg: wave 0 lanes 0..31 each own a column
    bool pred = false;
    if (tid < 32) {
        int m = -1;
        #pragma unroll
        for (int q = 0; q < SEG; ++q) m = max(m, sLE[q][tid]);
        pred = (m >= 0);
    }
    bool anyfg = __any(pred);
    if (tid == 0) hasfg_p[blk] = anyfg ? 1 : 0;

    // forward pass: u8-encode dl-1 (255 = no zero at-or-above)
    unsigned ap[SH / 4];
    {
        int le = carLE, ln = carLN;
        #pragma unroll
        for (int i = 0; i < SH; ++i) {
            int h = h0 + i;
            int tv = (tp[i >> 2] >> ((i & 3) * 8)) & 0xFF;
            int lz;
            if (tv == c) { le = h; lz = ln; } else { ln = h; lz = le; }
            unsigned a = (lz < 0) ? 255u : (unsigned)(h - lz - 1);
            if ((i & 3) == 0) ap[i >> 2] = 0;
            ap[i >> 2] |= a << ((i & 3) * 8);
        }
    }
    // backward pass: d = min(dl, dn), u16 store
    {
        int fe = carFE, fn = carFN;
        unsigned short* gk = gpk + (size_t)bc * HW_ + w;
        #pragma unroll
        for (int i = SH - 1; i >= 0; --i) {
            int h = h0 + i;
            int tv = (tp[i >> 2] >> ((i & 3) * 8)) & 0xFF;
            int nz; bool fg;
            if (tv == c) { fe = h; fg = true;  nz = fn; }
            else         { fn = h; fg = false; nz = fe; }
            unsigned au = (ap[i >> 2] >> ((i & 3) * 8)) & 0xFF;
            int dl  = (au == 255u) ? 0x7FFF : (int)au + 1;
            int dnx = (nz > 255) ? 0x7FFF : (nz - h);
            int d = min(dl, dnx);
            gk[h * W_] = (unsigned short)(d | (fg ? 0x8000 : 0));
        }
    }
}

// ---------------------------------------------------------------------------
// K1b: per-pixel softmax stats den = {max, 1/sum}. 1024 blocks x 256 thr x
// 2 px/thread (float2 loads, 512B/wave-inst) = 4096 waves (2x R7's branch).
// Separate dispatch -> per-kernel rocprof attribution of the old 47us.
// ---------------------------------------------------------------------------
__global__ void __launch_bounds__(256) k_sm(
                     const float* __restrict__ logits,
                     float2* __restrict__ den) {
    int tid = threadIdx.x;
    int pb = blockIdx.x;                   // [0, 1024)
    int b = pb >> 7;
    int p = ((pb & 127) << 9) + tid * 2;
    const float* lb = logits + (size_t)b * C_ * HW_ + p;
    float2 l[C_];
    float mxx = -3.4e38f, mxy = -3.4e38f;
    #pragma unroll
    for (int c = 0; c < C_; ++c) {
        l[c] = *(const float2*)(lb + (size_t)c * HW_);
        mxx = fmaxf(mxx, l[c].x);
        mxy = fmaxf(mxy, l[c].y);
    }
    float sx = 0.f, sy = 0.f;
    #pragma unroll
    for (int c = 0; c < C_; ++c) {
        sx += __expf(l[c].x - mxx);
        sy += __expf(l[c].y - mxy);
    }
    *(float4*)(den + (size_t)b * HW_ + p) =
        make_float4(mxx, 1.0f / sx, mxy, 1.0f / sy);
}

// ---------------------------------------------------------------------------
// K2 (fused): per-row horizontal EDT + own-class prob + raw dice sums.
// One wave per (bc,h) row; 4 rows (same bc) per block; no dt materialized.
// LDS: 128-float inf pads both sides (16.4KB/block -> 8 blocks/CU wave cap).
// Two-phase scan: r<=128 affine (ds_read2-mergeable); r>128 rare clamped tail.
// ---------------------------------------------------------------------------
__global__ void __launch_bounds__(256) k_edt(
                      const unsigned short* __restrict__ gpk,
                      const float* __restrict__ logits,
                      const float2* __restrict__ den,
                      const int* __restrict__ hasfg_p,
                      float* __restrict__ part) {
    __shared__ float sp[4][LROW_];
    __shared__ float sn[4][LROW_];
    int wave = threadIdx.x >> 6;
    int lane = threadIdx.x & 63;
    int row = blockIdx.x * 4 + wave;       // bc*256 + h; all 4 rows same bc
    int bc = row >> 8;
    int b = bc / C_, c = bc - b * C_;
    int h = row & (H_ - 1);

    int hfl = 0;
    if (lane < 8) hfl = hasfg_p[bc * 8 + lane];
    bool hf = __any(hfl != 0);             // uniform across block (same bc)

    // hoist independent prob-path loads: latency hides under the EDT scans
    const float*  lrow = logits + ((size_t)b * C_ + c) * HW_ + h * W_;
    const float2* drow = den + (size_t)b * HW_ + h * W_;
    float lv[4]; float2 mv[4];
    #pragma unroll
    for (int i = 0; i < 4; ++i) {
        int j = lane + 64 * i;
        lv[i] = lrow[j];
        mv[i] = drow[j];
    }

    float dv[4];
    if (hf) {
        const ushort4 v4 = ((const ushort4*)(gpk + (size_t)row * W_))[lane];

        // pad init: left pad = float4 slots [0,32), right pad = slots [96,128)
        float4 inf4 = make_float4(3.0e38f, 3.0e38f, 3.0e38f, 3.0e38f);
        int slot = (lane < 32) ? lane : (lane + 64);
        ((float4*)&sp[wave][0])[slot] = inf4;
        ((float4*)&sn[wave][0])[slot] = inf4;

        float s1 = (float)(1000000 - h);
        float sent2 = s1 * s1;             // == fl((1e6 - h)^2), reference-exact
        float4 fpv, fnv;
        {
            const unsigned short* vs = (const unsigned short*)&v4;
            float* fp = (float*)&fpv;
            float* fn = (float*)&fnv;
            #pragma unroll
            for (int q = 0; q < 4; ++q) {
                unsigned v = vs[q];
                unsigned d = v & 0x7FFFu;
                float g2 = (d == 0x7FFFu) ? sent2 : (float)(d * d);
                bool fg = (v & 0x8000u) != 0;
                fp[q] = fg ? g2 : 0.0f;
                fn[q] = fg ? 0.0f : g2;
            }
        }
        ((float4*)&sp[wave][PADL_])[lane] = fpv;   // data at [128, 384)
        ((float4*)&sn[wave][PADL_])[lane] = fnv;
        // wave-private LDS rows: wave-local wait suffices (no barrier)
        asm volatile("s_waitcnt lgkmcnt(0)" ::: "memory");

        float bp[4], bn[4];
        #pragma unroll
        for (int i = 0; i < 4; ++i) {
            int j = PADL_ + lane + 64 * i;
            bp[i] = sp[wave][j];
            bn[i] = sn[wave][j];
        }
        // ---- neg transform scan ----
        {
            bool doneN = false;
            int r = 1;
            for (; r <= PADL_; ++r) {          // affine fast path (ds_read2)
                float fr = (float)r;
                float r2 = fr * fr;
                float m = fmaxf(fmaxf(bn[0], bn[1]), fmaxf(bn[2], bn[3]));
                if (!__any(r2 < m)) { doneN = true; break; }
                #pragma unroll
                for (int i = 0; i < 4; ++i) {
                    int j = PADL_ + lane + 64 * i;
                    float v = fminf(sn[wave][j - r], sn[wave][j + r]);
                    bn[i] = fminf(bn[i], fmaf(fr, fr, v));
                }
            }
            if (!doneN) {
                for (; r < W_; ++r) {          // rare tail: clamped reads
                    float fr = (float)r;
                    float r2 = fr * fr;
                    float m = fmaxf(fmaxf(bn[0], bn[1]), fmaxf(bn[2], bn[3]));
                    if (!__any(r2 < m)) break;
                    #pragma unroll
                    for (int i = 0; i < 4; ++i) {
                        int j = PADL_ + lane + 64 * i;
                        int jm = max(j - r, 0);
                        int jp = min(j + r, LROW_ - 1);
                        float v = fminf(sn[wave][jm], sn[wave][jp]);
                        bn[i] = fminf(bn[i], fmaf(fr, fr, v));
                    }
                }
            }
        }
        // ---- pos transform scan ----
        {
            bool doneP = false;
            int r = 1;
            for (; r <= PADL_; ++r) {          // affine fast path (ds_read2)
                float fr = (float)r;
                float r2 = fr * fr;
                float m = fmaxf(fmaxf(bp[0], bp[1]), fmaxf(bp[2], bp[3]));
                if (!__any(r2 < m)) { doneP = true; break; }
                #pragma unroll
                for (int i = 0; i < 4; ++i) {
                    int j = PADL_ + lane + 64 * i;
                    float v = fminf(sp[wave][j - r], sp[wave][j + r]);
                    bp[i] = fminf(bp[i], fmaf(fr, fr, v));
                }
            }
            if (!doneP) {
                for (; r < W_; ++r) {          // rare tail: clamped reads
                    float fr = (float)r;
                    float r2 = fr * fr;
                    float m = fmaxf(fmaxf(bp[0], bp[1]), fmaxf(bp[2], bp[3]));
                    if (!__any(r2 < m)) break;
                    #pragma unroll
                    for (int i = 0; i < 4; ++i) {
                        int j = PADL_ + lane + 64 * i;
                        int jm = max(j - r, 0);
                        int jp = min(j + r, LROW_ - 1);
                        float v = fminf(sp[wave][jm], sp[wave][jp]);
                        bp[i] = fminf(bp[i], fmaf(fr, fr, v));
                    }
                }
            }
        }
        #pragma unroll
        for (int i = 0; i < 4; ++i) dv[i] = sqrtf(bn[i]) - sqrtf(bp[i]);
    } else {
        #pragma unroll
        for (int i = 0; i < 4; ++i) dv[i] = 0.0f;
    }

    // own-class prob from precomputed stats + raw sums over 256 pixels
    float s_pd = 0.f, s_p = 0.f, s_pp = 0.f, s_d = 0.f, s_dd = 0.f;
    float mn = 3.4e38f, mx = -3.4e38f;
    #pragma unroll
    for (int i = 0; i < 4; ++i) {
        float2 mi = mv[i];
        float pr = __expf(lv[i] - mi.x) * mi.y;
        float d = dv[i];
        s_pd = fmaf(pr, d, s_pd);
        s_p += pr;
        s_pp = fmaf(pr, pr, s_pp);
        s_d += d;
        s_dd = fmaf(d, d, s_dd);
        mn = fminf(mn, d);
        mx = fmaxf(mx, d);
    }
    #pragma unroll
    for (int off = 32; off; off >>= 1) {
        s_pd += __shfl_down(s_pd, off);
        s_p  += __shfl_down(s_p, off);
        s_pp += __shfl_down(s_pp, off);
        s_d  += __shfl_down(s_d, off);
        s_dd += __shfl_down(s_dd, off);
        mn = fminf(mn, __shfl_down(mn, off));
        mx = fmaxf(mx, __shfl_down(mx, off));
    }
    if (lane == 0) {
        float4* p4 = (float4*)(part + (size_t)row * 8);   // 32B-aligned
        p4[0] = make_float4(s_pd, s_p, s_pp, s_d);
        p4[1] = make_float4(s_dd, mn, mx, 0.0f);
    }
}

// ---------------------------------------------------------------------------
// K3: per-(b,c) reduce of 256 row partials -> dice -> atomicAdd loss term.
// out[0] zeroed by k_vert block 0. inter = sc*(S_pd - mn*S_p);
// d2 = sc^2*(S_dd - 2 mn S_d + mn^2 N). 96 atomics total.
// ---------------------------------------------------------------------------
__global__ void __launch_bounds__(256) k_bcred(
                       const float* __restrict__ part, float* __restrict__ out) {
    int bc = blockIdx.x;
    int tid = threadIdx.x;                 // 256
    const float4* p4 = (const float4*)(part + ((size_t)bc * 256 + tid) * 8);
    float4 a = p4[0], bq = p4[1];
    float s_pd = a.x, s_p = a.y, s_pp = a.z;
    float s_d = a.w, s_dd = bq.x, mn = bq.y, mx = bq.z;
    #pragma unroll
    for (int off = 32; off; off >>= 1) {
        s_pd += __shfl_down(s_pd, off);
        s_p  += __shfl_down(s_p, off);
        s_pp += __shfl_down(s_pp, off);
        s_d  += __shfl_down(s_d, off);
        s_dd += __shfl_down(s_dd, off);
        mn = fminf(mn, __shfl_down(mn, off));
        mx = fmaxf(mx, __shfl_down(mx, off));
    }
    __shared__ float red[4][7];
    int wave = tid >> 6, lane = tid & 63;
    if (lane == 0) {
        red[wave][0] = s_pd; red[wave][1] = s_p; red[wave][2] = s_pp;
        red[wave][3] = s_d;  red[wave][4] = s_dd; red[wave][5] = mn; red[wave][6] = mx;
    }
    __syncthreads();
    if (tid == 0) {
        s_pd = red[0][0]; s_p = red[0][1]; s_pp = red[0][2];
        s_d = red[0][3]; s_dd = red[0][4]; mn = red[0][5]; mx = red[0][6];
        for (int w = 1; w < 4; ++w) {
            s_pd += red[w][0]; s_p += red[w][1]; s_pp += red[w][2];
            s_d += red[w][3]; s_dd += red[w][4];
            mn = fminf(mn, red[w][5]); mx = fmaxf(mx, red[w][6]);
        }
        float sc = 1.0f / (mx - mn + 1e-8f);
        float inter = sc * (s_pd - mn * s_p);
        float d2 = sc * sc * (s_dd - 2.0f * mn * s_d + mn * mn * (float)HW_);
        float dice = 2.0f * inter / (s_pp + d2 + 1e-6f);
        atomicAdd(out, (1.0f - dice) * (1.0f / (float)NBC_));
    }
}

// ---------------------------------------------------------------------------
extern "C" void kernel_launch(void* const* d_in, const int* in_sizes, int n_in,
                              void* d_out, int out_size, void* d_ws, size_t ws_size,
                              hipStream_t stream) {
    const float* logits  = (const float*)d_in[0];
    const int*   targets = (const int*)d_in[1];
    float* out = (float*)d_out;

    // ws layout: gpk u16[96*65536] | hasfg_p i32[768] | part f32[24576*8] |
    //            den float2[8*65536]
    unsigned short* gpk = (unsigned short*)d_ws;
    int* hasfg_p = (int*)(gpk + (size_t)NBC_ * HW_);
    float* part = (float*)(hasfg_p + NBC_ * 8);
    float2* den = (float2*)(part + (size_t)NBC_ * H_ * 8);

    k_vert<<<VB_, 512, 0, stream>>>(targets, gpk, hasfg_p, out);
    k_sm<<<SMB_, 256, 0, stream>>>(logits, den);
    k_edt<<<NBC_ * H_ / 4, 256, 0, stream>>>(gpk, logits, den, hasfg_p, part);
    k_bcred<<<NBC_, 256, 0, stream>>>(part, out);
}

// Round 9
// 104.845 us; speedup vs baseline: 5.6731x; 1.0150x over previous
//
#include <hip/hip_runtime.h>
#include <math.h>

// Problem shape (fixed by setup_inputs): logits [8,12,256,256] fp32, targets [8,256,256] i32.
constexpr int B_  = 8;
constexpr int C_  = 12;
constexpr int H_  = 256;
constexpr int W_  = 256;
constexpr int HW_ = H_ * W_;
constexpr int NBC_ = B_ * C_;           // 96
constexpr int VB_  = NBC_ * 8;          // vert tiles (768): 32 columns per tile
constexpr int SMB_ = B_ * (HW_ / 1024); // probs blocks (512): 512 thr x 2 px
constexpr int PADL_ = 128;              // LDS pad: covers r<=128 affine reads
constexpr int LROW_ = PADL_ + W_ + PADL_;  // 512 floats per LDS row

// Packed vertical-EDT value: bit15 = is_fg (t==c); bits[14:0] = vertical
// distance d to nearest zero of the pixel's own nonzero transform
// (0x7FFF = no zero in column -> reference g = 1e6 - h). The OTHER
// transform's g is always 0 at this pixel, so one u16 encodes both.

// ---------------------------------------------------------------------------
// K1 (merged, 512 thr): blocks [0,768) = vertical EDT (32 cols x 16 segments
// x 16 rows); blocks [768,768+512) = softmax PROBS for all 12 classes
// (2 px/thread). Writing probs (25 MB) instead of den {max,1/sum} (4.2 MB)
// kills k_edt's 12x den re-read (50 MB) and its logits read (25 MB): net
// algorithmic HBM -54 MB, and k_edt loses the __expf per pixel.
// pr = __expf(l-mx)*(1/s): identical ops/order as before -> bit-identical.
// Block 0 zeroes out[0] (consumed by k_bcred two dispatches later).
// ---------------------------------------------------------------------------
__global__ void __launch_bounds__(512) k_vs(
                     const int* __restrict__ t,
                     const float* __restrict__ logits,
                     unsigned short* __restrict__ gpk,
                     int* __restrict__ hasfg_p,
                     float* __restrict__ probs,
                     float* __restrict__ out) {
    int tid = threadIdx.x;
    if (blockIdx.x >= VB_) {
        // ---- probs branch: 512 thr x 2 px, all 12 classes ----
        int pb = blockIdx.x - VB_;             // [0, 512)
        int b = pb >> 6;
        int p = ((pb & 63) << 10) + tid * 2;
        const float* lb = logits + (size_t)b * C_ * HW_ + p;
        float2 l[C_];
        float mxx = -3.4e38f, mxy = -3.4e38f;
        #pragma unroll
        for (int c = 0; c < C_; ++c) {
            l[c] = *(const float2*)(lb + (size_t)c * HW_);
            mxx = fmaxf(mxx, l[c].x);
            mxy = fmaxf(mxy, l[c].y);
        }
        float sx = 0.f, sy = 0.f;
        #pragma unroll
        for (int c = 0; c < C_; ++c) {
            l[c].x = __expf(l[c].x - mxx);     // in-place: e[c]
            l[c].y = __expf(l[c].y - mxy);
            sx += l[c].x;
            sy += l[c].y;
        }
        float ix = 1.0f / sx, iy = 1.0f / sy;
        float* pbp = probs + (size_t)b * C_ * HW_ + p;
        #pragma unroll
        for (int c = 0; c < C_; ++c) {
            *(float2*)(pbp + (size_t)c * HW_) = make_float2(l[c].x * ix, l[c].y * iy);
        }
        return;
    }

    // ---- vertical EDT branch (R8 geometry, proven) ----
    if (blockIdx.x == 0 && tid == 0) out[0] = 0.0f;   // replaces memset dispatch
    constexpr int SEG = 16, SH = 16;
    int s  = tid >> 5;          // segment 0..15
    int wl = tid & 31;          // column within tile
    int blk = blockIdx.x;       // 96*8
    int bc = blk >> 3;
    int w0 = (blk & 7) * 32;
    int b = bc / C_, c = bc - b * C_;
    int w = w0 + wl;
    const int* base = t + b * HW_ + w;
    int h0 = s * SH;

    unsigned tp[SH / 4];        // 4 regs: u8-packed targets for this segment
    int lastEq = -1, lastNeq = -1, firstEq = 256, firstNeq = 256;
    #pragma unroll
    for (int i = 0; i < SH; ++i) {
        int tv = base[(h0 + i) * W_];
        if ((i & 3) == 0) tp[i >> 2] = 0;
        tp[i >> 2] |= (unsigned)tv << ((i & 3) * 8);
        int h = h0 + i;
        if (tv == c) { lastEq = h;  if (firstEq  == 256) firstEq  = h; }
        else         { lastNeq = h; if (firstNeq == 256) firstNeq = h; }
    }
    __shared__ int sLE[SEG][32], sLN[SEG][32], sFE[SEG][32], sFN[SEG][32];
    sLE[s][wl] = lastEq; sLN[s][wl] = lastNeq;
    sFE[s][wl] = firstEq; sFN[s][wl] = firstNeq;
    __syncthreads();

    int carLE = -1, carLN = -1;
    for (int q = 0; q < s; ++q) {
        carLE = max(carLE, sLE[q][wl]);
        carLN = max(carLN, sLN[q][wl]);
    }
    int carFE = 256, carFN = 256;
    for (int q = s + 1; q < SEG; ++q) {
        carFE = min(carFE, sFE[q][wl]);
        carFN = min(carFN, sFN[q][wl]);
    }

    // tile has-fg: wave 0 lanes 0..31 each own a column
    bool pred = false;
    if (tid < 32) {
        int m = -1;
        #pragma unroll
        for (int q = 0; q < SEG; ++q) m = max(m, sLE[q][tid]);
        pred = (m >= 0);
    }
    bool anyfg = __any(pred);
    if (tid == 0) hasfg_p[blk] = anyfg ? 1 : 0;

    // forward pass: u8-encode dl-1 (255 = no zero at-or-above)
    unsigned ap[SH / 4];
    {
        int le = carLE, ln = carLN;
        #pragma unroll
        for (int i = 0; i < SH; ++i) {
            int h = h0 + i;
            int tv = (tp[i >> 2] >> ((i & 3) * 8)) & 0xFF;
            int lz;
            if (tv == c) { le = h; lz = ln; } else { ln = h; lz = le; }
            unsigned a = (lz < 0) ? 255u : (unsigned)(h - lz - 1);
            if ((i & 3) == 0) ap[i >> 2] = 0;
            ap[i >> 2] |= a << ((i & 3) * 8);
        }
    }
    // backward pass: d = min(dl, dn), u16 store
    {
        int fe = carFE, fn = carFN;
        unsigned short* gk = gpk + (size_t)bc * HW_ + w;
        #pragma unroll
        for (int i = SH - 1; i >= 0; --i) {
            int h = h0 + i;
            int tv = (tp[i >> 2] >> ((i & 3) * 8)) & 0xFF;
            int nz; bool fg;
            if (tv == c) { fe = h; fg = true;  nz = fn; }
            else         { fn = h; fg = false; nz = fe; }
            unsigned au = (ap[i >> 2] >> ((i & 3) * 8)) & 0xFF;
            int dl  = (au == 255u) ? 0x7FFF : (int)au + 1;
            int dnx = (nz > 255) ? 0x7FFF : (nz - h);
            int d = min(dl, dnx);
            gk[h * W_] = (unsigned short)(d | (fg ? 0x8000 : 0));
        }
    }
}

// ---------------------------------------------------------------------------
// K2 (fused): per-row horizontal EDT + raw dice sums. One wave per (bc,h)
// row; 4 rows (same bc) per block. Own-class prob now a direct load from
// probs (no logits read, no den read, no __expf).
// LDS: 128-float inf pads both sides (16.4KB/block -> 8 blocks/CU wave cap).
// Two-phase scan: r<=128 affine (ds_read2-mergeable); r>128 rare clamped tail.
// ---------------------------------------------------------------------------
__global__ void __launch_bounds__(256) k_edt(
                      const unsigned short* __restrict__ gpk,
                      const float* __restrict__ probs,
                      const int* __restrict__ hasfg_p,
                      float* __restrict__ part) {
    __shared__ float sp[4][LROW_];
    __shared__ float sn[4][LROW_];
    int wave = threadIdx.x >> 6;
    int lane = threadIdx.x & 63;
    int row = blockIdx.x * 4 + wave;       // bc*256 + h; all 4 rows same bc
    int bc = row >> 8;
    int h = row & (H_ - 1);

    int hfl = 0;
    if (lane < 8) hfl = hasfg_p[bc * 8 + lane];
    bool hf = __any(hfl != 0);             // uniform across block (same bc)

    // hoist the prob loads: latency hides under the EDT scans
    const float* prow = probs + (size_t)bc * HW_ + h * W_;
    float pv[4];
    #pragma unroll
    for (int i = 0; i < 4; ++i) pv[i] = prow[lane + 64 * i];

    float dv[4];
    if (hf) {
        const ushort4 v4 = ((const ushort4*)(gpk + (size_t)row * W_))[lane];

        // pad init: left pad = float4 slots [0,32), right pad = slots [96,128)
        float4 inf4 = make_float4(3.0e38f, 3.0e38f, 3.0e38f, 3.0e38f);
        int slot = (lane < 32) ? lane : (lane + 64);
        ((float4*)&sp[wave][0])[slot] = inf4;
        ((float4*)&sn[wave][0])[slot] = inf4;

        float s1 = (float)(1000000 - h);
        float sent2 = s1 * s1;             // == fl((1e6 - h)^2), reference-exact
        float4 fpv, fnv;
        {
            const unsigned short* vs = (const unsigned short*)&v4;
            float* fp = (float*)&fpv;
            float* fn = (float*)&fnv;
            #pragma unroll
            for (int q = 0; q < 4; ++q) {
                unsigned v = vs[q];
                unsigned d = v & 0x7FFFu;
                float g2 = (d == 0x7FFFu) ? sent2 : (float)(d * d);
                bool fg = (v & 0x8000u) != 0;
                fp[q] = fg ? g2 : 0.0f;
                fn[q] = fg ? 0.0f : g2;
            }
        }
        ((float4*)&sp[wave][PADL_])[lane] = fpv;   // data at [128, 384)
        ((float4*)&sn[wave][PADL_])[lane] = fnv;
        // wave-private LDS rows: wave-local wait suffices (no barrier)
        asm volatile("s_waitcnt lgkmcnt(0)" ::: "memory");

        float bp[4], bn[4];
        #pragma unroll
        for (int i = 0; i < 4; ++i) {
            int j = PADL_ + lane + 64 * i;
            bp[i] = sp[wave][j];
            bn[i] = sn[wave][j];
        }
        // ---- neg transform scan ----
        {
            bool doneN = false;
            int r = 1;
            for (; r <= PADL_; ++r) {          // affine fast path (ds_read2)
                float fr = (float)r;
                float r2 = fr * fr;
                float m = fmaxf(fmaxf(bn[0], bn[1]), fmaxf(bn[2], bn[3]));
                if (!__any(r2 < m)) { doneN = true; break; }
                #pragma unroll
                for (int i = 0; i < 4; ++i) {
                    int j = PADL_ + lane + 64 * i;
                    float v = fminf(sn[wave][j - r], sn[wave][j + r]);
                    bn[i] = fminf(bn[i], fmaf(fr, fr, v));
                }
            }
            if (!doneN) {
                for (; r < W_; ++r) {          // rare tail: clamped reads
                    float fr = (float)r;
                    float r2 = fr * fr;
                    float m = fmaxf(fmaxf(bn[0], bn[1]), fmaxf(bn[2], bn[3]));
                    if (!__any(r2 < m)) break;
                    #pragma unroll
                    for (int i = 0; i < 4; ++i) {
                        int j = PADL_ + lane + 64 * i;
                        int jm = max(j - r, 0);
                        int jp = min(j + r, LROW_ - 1);
                        float v = fminf(sn[wave][jm], sn[wave][jp]);
                        bn[i] = fminf(bn[i], fmaf(fr, fr, v));
                    }
                }
            }
        }
        // ---- pos transform scan ----
        {
            bool doneP = false;
            int r = 1;
            for (; r <= PADL_; ++r) {          // affine fast path (ds_read2)
                float fr = (float)r;
                float r2 = fr * fr;
                float m = fmaxf(fmaxf(bp[0], bp[1]), fmaxf(bp[2], bp[3]));
                if (!__any(r2 < m)) { doneP = true; break; }
                #pragma unroll
                for (int i = 0; i < 4; ++i) {
                    int j = PADL_ + lane + 64 * i;
                    float v = fminf(sp[wave][j - r], sp[wave][j + r]);
                    bp[i] = fminf(bp[i], fmaf(fr, fr, v));
                }
            }
            if (!doneP) {
                for (; r < W_; ++r) {          // rare tail: clamped reads
                    float fr = (float)r;
                    float r2 = fr * fr;
                    float m = fmaxf(fmaxf(bp[0], bp[1]), fmaxf(bp[2], bp[3]));
                    if (!__any(r2 < m)) break;
                    #pragma unroll
                    for (int i = 0; i < 4; ++i) {
                        int j = PADL_ + lane + 64 * i;
                        int jm = max(j - r, 0);
                        int jp = min(j + r, LROW_ - 1);
                        float v = fminf(sp[wave][jm], sp[wave][jp]);
                        bp[i] = fminf(bp[i], fmaf(fr, fr, v));
                    }
                }
            }
        }
        #pragma unroll
        for (int i = 0; i < 4; ++i) dv[i] = sqrtf(bn[i]) - sqrtf(bp[i]);
    } else {
        #pragma unroll
        for (int i = 0; i < 4; ++i) dv[i] = 0.0f;
    }

    // raw sums over 256 pixels (pr from probs; order identical to before)
    float s_pd = 0.f, s_p = 0.f, s_pp = 0.f, s_d = 0.f, s_dd = 0.f;
    float mn = 3.4e38f, mx = -3.4e38f;
    #pragma unroll
    for (int i = 0; i < 4; ++i) {
        float pr = pv[i];
        float d = dv[i];
        s_pd = fmaf(pr, d, s_pd);
        s_p += pr;
        s_pp = fmaf(pr, pr, s_pp);
        s_d += d;
        s_dd = fmaf(d, d, s_dd);
        mn = fminf(mn, d);
        mx = fmaxf(mx, d);
    }
    #pragma unroll
    for (int off = 32; off; off >>= 1) {
        s_pd += __shfl_down(s_pd, off);
        s_p  += __shfl_down(s_p, off);
        s_pp += __shfl_down(s_pp, off);
        s_d  += __shfl_down(s_d, off);
        s_dd += __shfl_down(s_dd, off);
        mn = fminf(mn, __shfl_down(mn, off));
        mx = fmaxf(mx, __shfl_down(mx, off));
    }
    if (lane == 0) {
        float4* p4 = (float4*)(part + (size_t)row * 8);   // 32B-aligned
        p4[0] = make_float4(s_pd, s_p, s_pp, s_d);
        p4[1] = make_float4(s_dd, mn, mx, 0.0f);
    }
}

// ---------------------------------------------------------------------------
// K3: per-(b,c) reduce of 256 row partials -> dice -> atomicAdd loss term.
// out[0] zeroed by k_vs block 0. inter = sc*(S_pd - mn*S_p);
// d2 = sc^2*(S_dd - 2 mn S_d + mn^2 N). 96 atomics total.
// ---------------------------------------------------------------------------
__global__ void __launch_bounds__(256) k_bcred(
                       const float* __restrict__ part, float* __restrict__ out) {
    int bc = blockIdx.x;
    int tid = threadIdx.x;                 // 256
    const float4* p4 = (const float4*)(part + ((size_t)bc * 256 + tid) * 8);
    float4 a = p4[0], bq = p4[1];
    float s_pd = a.x, s_p = a.y, s_pp = a.z;
    float s_d = a.w, s_dd = bq.x, mn = bq.y, mx = bq.z;
    #pragma unroll
    for (int off = 32; off; off >>= 1) {
        s_pd += __shfl_down(s_pd, off);
        s_p  += __shfl_down(s_p, off);
        s_pp += __shfl_down(s_pp, off);
        s_d  += __shfl_down(s_d, off);
        s_dd += __shfl_down(s_dd, off);
        mn = fminf(mn, __shfl_down(mn, off));
        mx = fmaxf(mx, __shfl_down(mx, off));
    }
    __shared__ float red[4][7];
    int wave = tid >> 6, lane = tid & 63;
    if (lane == 0) {
        red[wave][0] = s_pd; red[wave][1] = s_p; red[wave][2] = s_pp;
        red[wave][3] = s_d;  red[wave][4] = s_dd; red[wave][5] = mn; red[wave][6] = mx;
    }
    __syncthreads();
    if (tid == 0) {
        s_pd = red[0][0]; s_p = red[0][1]; s_pp = red[0][2];
        s_d = red[0][3]; s_dd = red[0][4]; mn = red[0][5]; mx = red[0][6];
        for (int w = 1; w < 4; ++w) {
            s_pd += red[w][0]; s_p += red[w][1]; s_pp += red[w][2];
            s_d += red[w][3]; s_dd += red[w][4];
            mn = fminf(mn, red[w][5]); mx = fmaxf(mx, red[w][6]);
        }
        float sc = 1.0f / (mx - mn + 1e-8f);
        float inter = sc * (s_pd - mn * s_p);
        float d2 = sc * sc * (s_dd - 2.0f * mn * s_d + mn * mn * (float)HW_);
        float dice = 2.0f * inter / (s_pp + d2 + 1e-6f);
        atomicAdd(out, (1.0f - dice) * (1.0f / (float)NBC_));
    }
}

// ---------------------------------------------------------------------------
extern "C" void kernel_launch(void* const* d_in, const int* in_sizes, int n_in,
                              void* d_out, int out_size, void* d_ws, size_t ws_size,
                              hipStream_t stream) {
    const float* logits  = (const float*)d_in[0];
    const int*   targets = (const int*)d_in[1];
    float* out = (float*)d_out;

    // ws layout: gpk u16[96*65536] | hasfg_p i32[768] | part f32[24576*8] |
    //            probs f32[8*12*65536]
    unsigned short* gpk = (unsigned short*)d_ws;
    int* hasfg_p = (int*)(gpk + (size_t)NBC_ * HW_);
    float* part = (float*)(hasfg_p + NBC_ * 8);
    float* probs = part + (size_t)NBC_ * H_ * 8;

    k_vs<<<VB_ + SMB_, 512, 0, stream>>>(targets, logits, gpk,
                                         hasfg_p, probs, out);
    k_edt<<<NBC_ * H_ / 4, 256, 0, stream>>>(gpk, probs, hasfg_p, part);
    k_bcred<<<NBC_, 256, 0, stream>>>(part, out);
}